// Round 1
// baseline (4558.264 us; speedup 1.0000x reference)
//
#include <hip/hip_runtime.h>
#include <math.h>

// ---------------- problem constants ----------------
constexpr int kH = 48, kW = 64, kHW = 3072, kC = 256;
constexpr int kHidden = 128, kCtx = 64;
constexpr int kLevels = 4, kP = 81, kCorrDim = 324;  // 81*4
constexpr int kNS = 37, kTopK = 3, kIters = 4;
constexpr int kGin = kHidden + kCorrDim + kCtx;      // 516

// ---------------- workspace layout (float offsets) ----------------
constexpr size_t OFF_CORR0 = 0;                                   // 3072*3072
constexpr size_t OFF_CORR1 = OFF_CORR0 + (size_t)kHW * 3072;      // 3072*768
constexpr size_t OFF_CORR2 = OFF_CORR1 + (size_t)kHW * 768;       // 3072*192
constexpr size_t OFF_CORR3 = OFF_CORR2 + (size_t)kHW * 192;       // 3072*48
constexpr size_t OFF_X     = OFF_CORR3 + (size_t)kHW * 48;        // 3072*3
constexpr size_t OFF_BUF1  = OFF_X + (size_t)kHW * 3;             // 516*3072 (h|fused|ctx)
constexpr size_t OFF_RH    = OFF_BUF1 + (size_t)kGin * kHW;       // 128*3072
constexpr size_t OFF_ZPRE  = OFF_RH   + (size_t)kHidden * kHW;
constexpr size_t OFF_RPRE  = OFF_ZPRE + (size_t)kHidden * kHW;
constexpr size_t OFF_QPRE  = OFF_RPRE + (size_t)kHidden * kHW;
constexpr size_t OFF_SAMP  = OFF_QPRE + (size_t)kHidden * kHW;    // 37*12 (R,t)
constexpr size_t OFF_CONF  = OFF_SAMP + 448;                      // 37
constexpr size_t OFF_TK    = OFF_CONF + 64;                       // 3 floats w + 3 ints idx
constexpr size_t OFF_POSE  = OFF_TK + 16;                         // 7
constexpr size_t OFF_FEAT  = OFF_POSE + 16;                       // 128

// ---------------- sample templates ----------------
__constant__ float c_rot[12][3] = {
  {0,0,0},{0,0,0},{0,0,0},{0,0,0},{0,0,0},{0,0,0},
  {1,0,0},{-1,0,0},{0,1,0},{0,-1,0},{0,0,1},{0,0,-1}};
__constant__ float c_trs[12][3] = {
  {1,0,0},{-1,0,0},{0,1,0},{0,-1,0},{0,0,1},{0,0,-1},
  {0,0,0},{0,0,0},{0,0,0},{0,0,0},{0,0,0},{0,0,0}};

// ---------------- device helpers ----------------
__device__ inline void d_qmul(const float* q, const float* r, float* o) {
  o[0] = q[0]*r[0] - q[1]*r[1] - q[2]*r[2] - q[3]*r[3];
  o[1] = q[0]*r[1] + q[1]*r[0] + q[2]*r[3] - q[3]*r[2];
  o[2] = q[0]*r[2] - q[1]*r[3] + q[2]*r[0] + q[3]*r[1];
  o[3] = q[0]*r[3] + q[1]*r[2] - q[2]*r[1] + q[3]*r[0];
}
// rotate v by quaternion q: qmul(qmul(q,(0,v)), conj(q))[1:4]
__device__ inline void d_qapply(const float* q, const float* v, float* o) {
  float a0 = -q[1]*v[0] - q[2]*v[1] - q[3]*v[2];
  float a1 =  q[0]*v[0] + q[2]*v[2] - q[3]*v[1];
  float a2 =  q[0]*v[1] - q[1]*v[2] + q[3]*v[0];
  float a3 =  q[0]*v[2] + q[1]*v[1] - q[2]*v[0];
  o[0] = -a0*q[1] + a1*q[0] - a2*q[3] + a3*q[2];
  o[1] = -a0*q[2] + a1*q[3] + a2*q[0] - a3*q[1];
  o[2] = -a0*q[3] - a1*q[2] + a2*q[1] + a3*q[0];
}
__device__ inline void d_intr(const float* intr, float& fx, float& fy, float& cx, float& cy) {
  fx = 60.f + 40.f*intr[0];
  fy = 60.f + 40.f*intr[1];
  cx = 32.f + 4.f*(intr[2] - 0.5f);
  cy = 24.f + 4.f*(intr[3] - 0.5f);
}
// sum of 4 bilinear taps with zero-padding validity, reading from LDS row
__device__ inline float bil_tap(const float* row_s, int base, int Wl, int Hl,
                                int X0, int Y0, float fxr, float fyr) {
  float acc = 0.f;
  float w00 = (1.f - fxr)*(1.f - fyr), w10 = fxr*(1.f - fyr);
  float w01 = (1.f - fxr)*fyr,         w11 = fxr*fyr;
  bool vx0 = (X0 >= 0) & (X0 < Wl);
  bool vx1 = (X0 + 1 >= 0) & (X0 + 1 < Wl);
  if (Y0 >= 0 && Y0 < Hl) {
    int rb = base + Y0*Wl;
    if (vx0) acc += w00 * row_s[rb + X0];
    if (vx1) acc += w10 * row_s[rb + X0 + 1];
  }
  if (Y0 + 1 >= 0 && Y0 + 1 < Hl) {
    int rb = base + (Y0 + 1)*Wl;
    if (vx0) acc += w01 * row_s[rb + X0];
    if (vx1) acc += w11 * row_s[rb + X0 + 1];
  }
  return acc;
}

// ---------------- init: zero h, copy context, init pose ----------------
__global__ void init_k(const float* __restrict__ ctx, float* __restrict__ buf1,
                       float* __restrict__ pose) {
  int idx = blockIdx.x * blockDim.x + threadIdx.x;
  if (idx < kHidden * kHW) buf1[idx] = 0.f;
  if (idx < kCtx * kHW) buf1[(size_t)(kHidden + kCorrDim) * kHW + idx] = ctx[idx];
  if (idx == 0) {
    pose[0] = 1.f;
    for (int j = 1; j < 7; ++j) pose[j] = 0.f;
  }
}

// ---------------- corr GEMM: C[i,q] = sum_c A[c,i]*B[c,q] / 16 ----------------
__global__ __launch_bounds__(256) void corr_gemm_k(const float* __restrict__ A,
                                                   const float* __restrict__ Bm,
                                                   float* __restrict__ Cg) {
  __shared__ __align__(16) float As[8 * 128];
  __shared__ __align__(16) float Bs[8 * 128];
  int tid = threadIdx.x;
  int tx = tid % 16, ty = tid / 16;
  int q0 = blockIdx.x * 128, i0 = blockIdx.y * 128;
  float acc[8][8];
#pragma unroll
  for (int r = 0; r < 8; ++r)
#pragma unroll
    for (int c = 0; c < 8; ++c) acc[r][c] = 0.f;

  int cl = tid / 32;
  int col = (tid % 32) * 4;
  for (int c0 = 0; c0 < kC; c0 += 8) {
    *(float4*)&As[cl * 128 + col] = *(const float4*)&A[(size_t)(c0 + cl) * kHW + i0 + col];
    *(float4*)&Bs[cl * 128 + col] = *(const float4*)&Bm[(size_t)(c0 + cl) * kHW + q0 + col];
    __syncthreads();
#pragma unroll
    for (int k = 0; k < 8; ++k) {
      float4 a0 = *(const float4*)&As[k * 128 + ty * 8];
      float4 a1 = *(const float4*)&As[k * 128 + ty * 8 + 4];
      float4 b0 = *(const float4*)&Bs[k * 128 + tx * 8];
      float4 b1 = *(const float4*)&Bs[k * 128 + tx * 8 + 4];
      float a[8] = {a0.x, a0.y, a0.z, a0.w, a1.x, a1.y, a1.z, a1.w};
      float b[8] = {b0.x, b0.y, b0.z, b0.w, b1.x, b1.y, b1.z, b1.w};
#pragma unroll
      for (int r = 0; r < 8; ++r)
#pragma unroll
        for (int c = 0; c < 8; ++c) acc[r][c] = fmaf(a[r], b[c], acc[r][c]);
    }
    __syncthreads();
  }
  const float S = 0.0625f;  // 1/sqrt(256)
#pragma unroll
  for (int r = 0; r < 8; ++r) {
    size_t base = (size_t)(i0 + ty * 8 + r) * kHW + q0 + tx * 8;
    float4 o0 = {acc[r][0]*S, acc[r][1]*S, acc[r][2]*S, acc[r][3]*S};
    float4 o1 = {acc[r][4]*S, acc[r][5]*S, acc[r][6]*S, acc[r][7]*S};
    *(float4*)&Cg[base] = o0;
    *(float4*)&Cg[base + 4] = o1;
  }
}

// ---------------- 2x2 avg pool per row ----------------
__global__ void pool2_k(const float* __restrict__ in, float* __restrict__ out,
                        int Hi, int Wi) {
  int Ho = Hi / 2, Wo = Wi / 2;
  int total = kHW * Ho * Wo;
  int idx = blockIdx.x * blockDim.x + threadIdx.x;
  if (idx >= total) return;
  int i = idx / (Ho * Wo);
  int r = idx % (Ho * Wo);
  int y = r / Wo, x = r % Wo;
  const float* p = in + (size_t)i * Hi * Wi;
  out[idx] = 0.25f * (p[(2*y)*Wi + 2*x] + p[(2*y)*Wi + 2*x + 1] +
                      p[(2*y+1)*Wi + 2*x] + p[(2*y+1)*Wi + 2*x + 1]);
}

// ---------------- back-projection ----------------
__global__ void xpts_k(const float* __restrict__ depth, const float* __restrict__ intr,
                       float* __restrict__ X) {
  int p = blockIdx.x * blockDim.x + threadIdx.x;
  if (p >= kHW) return;
  float fx, fy, cx, cy;
  d_intr(intr, fx, fy, cx, cy);
  float d = 4.f + 20.f * depth[p];
  float u = (float)(p % kW), v = (float)(p / kW);
  X[p*3+0] = (u - cx) / fx * d;
  X[p*3+1] = (v - cy) / fy * d;
  X[p*3+2] = d;
}

// ---------------- per-iteration: sample poses (R,t), zero conf & feat ----------------
__global__ void sample_poses_k(const float* __restrict__ pose, float* __restrict__ samp,
                               float* __restrict__ conf, float* __restrict__ feat) {
  int t = threadIdx.x;
  if (t < kNS) conf[t] = 0.f;
  if (t < kHidden) feat[t] = 0.f;
  if (t >= kNS) return;
  float qc[4] = {pose[0], pose[1], pose[2], pose[3]};
  float tc[3] = {pose[4], pose[5], pose[6]};
  float dq[4], dt[3];
  if (t == 36) {
    dq[0] = 1.f; dq[1] = dq[2] = dq[3] = 0.f;
    dt[0] = dt[1] = dt[2] = 0.f;
  } else {
    int j = t / 3, k = t % 3;
    float sc = (k == 0) ? 0.25f : ((k == 1) ? 1.f : 4.f);
    float rx = c_rot[j][0], ry = c_rot[j][1], rz = c_rot[j][2];
    float nrm = sqrtf(rx*rx + ry*ry + rz*rz);
    float axn = fmaxf(nrm, 1e-8f);
    float ax = rx / axn, ay = ry / axn, az = rz / axn;
    float ha = 0.02f * sc * 0.5f;
    float sh = sinf(ha), ch = cosf(ha);
    dq[0] = ch; dq[1] = ax * sh; dq[2] = ay * sh; dq[3] = az * sh;
    dt[0] = c_trs[j][0] * (0.02f * sc);
    dt[1] = c_trs[j][1] * (0.02f * sc);
    dt[2] = c_trs[j][2] * (0.02f * sc);
  }
  float qn[4];
  d_qmul(qc, dq, qn);
  float inv = 1.f / sqrtf(qn[0]*qn[0] + qn[1]*qn[1] + qn[2]*qn[2] + qn[3]*qn[3]);
  qn[0] *= inv; qn[1] *= inv; qn[2] *= inv; qn[3] *= inv;
  float tr[3];
  d_qapply(qc, dt, tr);
  float w = qn[0], x = qn[1], y = qn[2], z = qn[3];
  float* S = samp + t * 12;
  S[0] = 1.f - 2.f*(y*y + z*z); S[1] = 2.f*(x*y - w*z);       S[2] = 2.f*(x*z + w*y);
  S[3] = 2.f*(x*y + w*z);       S[4] = 1.f - 2.f*(x*x + z*z); S[5] = 2.f*(y*z - w*x);
  S[6] = 2.f*(x*z - w*y);       S[7] = 2.f*(y*z + w*x);       S[8] = 1.f - 2.f*(x*x + y*y);
  S[9]  = tc[0] + tr[0];
  S[10] = tc[1] + tr[1];
  S[11] = tc[2] + tr[2];
}

// ---------------- conf: one block per source pixel i ----------------
__global__ __launch_bounds__(256) void conf_k(const float* __restrict__ corr0,
                                              const float* __restrict__ corr1,
                                              const float* __restrict__ corr2,
                                              const float* __restrict__ corr3,
                                              const float* __restrict__ X,
                                              const float* __restrict__ samp,
                                              const float* __restrict__ intr,
                                              float* __restrict__ conf) {
  __shared__ float row_s[4080];
  __shared__ float s_fx[kNS * 4], s_fy[kNS * 4];
  __shared__ int   s_ix[kNS * 4], s_iy[kNS * 4];
  __shared__ float s_conf[kNS];
  const int i = blockIdx.x;
  const int tid = threadIdx.x;

  for (int idx = tid; idx < 4080; idx += 256) {
    float v;
    if (idx < 3072)      v = corr0[(size_t)i * 3072 + idx];
    else if (idx < 3840) v = corr1[(size_t)i * 768 + idx - 3072];
    else if (idx < 4032) v = corr2[(size_t)i * 192 + idx - 3840];
    else                 v = corr3[(size_t)i * 48 + idx - 4032];
    row_s[idx] = v;
  }
  if (tid < kNS) {
    s_conf[tid] = 0.f;
    const float* S = samp + tid * 12;
    float X0 = X[i*3], X1 = X[i*3+1], X2 = X[i*3+2];
    float xc0 = S[0]*X0 + S[1]*X1 + S[2]*X2 + S[9];
    float xc1 = S[3]*X0 + S[4]*X1 + S[5]*X2 + S[10];
    float xc2 = S[6]*X0 + S[7]*X1 + S[8]*X2 + S[11];
    float z = fmaxf(xc2, 0.1f);
    float fx, fy, cx, cy;
    d_intr(intr, fx, fy, cx, cy);
    float u = fx * xc0 / z + cx;
    float v = fy * xc1 / z + cy;
#pragma unroll
    for (int l = 0; l < 4; ++l) {
      float s = (float)(1 << l);
      float bx = u / s, by = v / s;
      float fbx = floorf(bx), fby = floorf(by);
      s_ix[tid*4 + l] = (int)fbx;
      s_iy[tid*4 + l] = (int)fby;
      s_fx[tid*4 + l] = bx - fbx;
      s_fy[tid*4 + l] = by - fby;
    }
  }
  __syncthreads();

  const int lvl_off[4] = {0, 3072, 3840, 4032};
  for (int n = 0; n < kNS; ++n) {
    float local = 0.f;
    for (int d = tid; d < kCorrDim; d += 256) {
      int lvl = d / kP;
      int o = d % kP;
      int oyi = o / 9 - 4, oxi = o % 9 - 4;
      int Wl = kW >> lvl, Hl = kH >> lvl;
      int X0 = s_ix[n*4 + lvl] + oxi;
      int Y0 = s_iy[n*4 + lvl] + oyi;
      local += bil_tap(row_s, lvl_off[lvl], Wl, Hl, X0, Y0,
                       s_fx[n*4 + lvl], s_fy[n*4 + lvl]);
    }
#pragma unroll
    for (int off = 32; off; off >>= 1) local += __shfl_xor(local, off, 64);
    if ((tid & 63) == 0) atomicAdd(&s_conf[n], local);
  }
  __syncthreads();
  if (tid < kNS) atomicAdd(&conf[tid], s_conf[tid]);
}

// ---------------- top-k + softmax (tiny) ----------------
__global__ void topk_k(const float* __restrict__ conf, float* __restrict__ tkw,
                       int* __restrict__ tki) {
  if (threadIdx.x != 0) return;
  const float scale = 1.f / ((float)kHW * (float)kCorrDim);
  float c[kNS];
  for (int n = 0; n < kNS; ++n) c[n] = conf[n] * scale;
  int id[3] = {-1, -1, -1};
  float v[3];
  for (int k = 0; k < 3; ++k) {
    float best = -1e30f;
    int bi = -1;
    for (int n = 0; n < kNS; ++n) {
      if (n == id[0] || n == id[1] || n == id[2]) continue;
      if (c[n] > best) { best = c[n]; bi = n; }
    }
    v[k] = best;
    id[k] = bi;
  }
  float m = v[0];
  float e0 = expf(v[0] - m), e1 = expf(v[1] - m), e2 = expf(v[2] - m);
  float s = e0 + e1 + e2;
  tkw[0] = e0 / s; tkw[1] = e1 / s; tkw[2] = e2 / s;
  tki[0] = id[0]; tki[1] = id[1]; tki[2] = id[2];
}

// ---------------- fused correlation features for top-3 ----------------
__global__ __launch_bounds__(256) void fused_k(const float* __restrict__ corr0,
                                               const float* __restrict__ corr1,
                                               const float* __restrict__ corr2,
                                               const float* __restrict__ corr3,
                                               const float* __restrict__ X,
                                               const float* __restrict__ samp,
                                               const float* __restrict__ intr,
                                               const float* __restrict__ tkw,
                                               const int* __restrict__ tki,
                                               float* __restrict__ buf1) {
  __shared__ float row_s[4080];
  __shared__ float s_fx[12], s_fy[12];
  __shared__ int   s_ix[12], s_iy[12];
  __shared__ float s_w[3];
  const int i = blockIdx.x;
  const int tid = threadIdx.x;

  for (int idx = tid; idx < 4080; idx += 256) {
    float v;
    if (idx < 3072)      v = corr0[(size_t)i * 3072 + idx];
    else if (idx < 3840) v = corr1[(size_t)i * 768 + idx - 3072];
    else if (idx < 4032) v = corr2[(size_t)i * 192 + idx - 3840];
    else                 v = corr3[(size_t)i * 48 + idx - 4032];
    row_s[idx] = v;
  }
  if (tid < 3) {
    int n = tki[tid];
    s_w[tid] = tkw[tid];
    const float* S = samp + n * 12;
    float X0 = X[i*3], X1 = X[i*3+1], X2 = X[i*3+2];
    float xc0 = S[0]*X0 + S[1]*X1 + S[2]*X2 + S[9];
    float xc1 = S[3]*X0 + S[4]*X1 + S[5]*X2 + S[10];
    float xc2 = S[6]*X0 + S[7]*X1 + S[8]*X2 + S[11];
    float z = fmaxf(xc2, 0.1f);
    float fx, fy, cx, cy;
    d_intr(intr, fx, fy, cx, cy);
    float u = fx * xc0 / z + cx;
    float v = fy * xc1 / z + cy;
#pragma unroll
    for (int l = 0; l < 4; ++l) {
      float s = (float)(1 << l);
      float bx = u / s, by = v / s;
      float fbx = floorf(bx), fby = floorf(by);
      s_ix[tid*4 + l] = (int)fbx;
      s_iy[tid*4 + l] = (int)fby;
      s_fx[tid*4 + l] = bx - fbx;
      s_fy[tid*4 + l] = by - fby;
    }
  }
  __syncthreads();

  const int lvl_off[4] = {0, 3072, 3840, 4032};
  for (int d = tid; d < kCorrDim; d += 256) {
    int lvl = d / kP;
    int o = d % kP;
    int oyi = o / 9 - 4, oxi = o % 9 - 4;
    int Wl = kW >> lvl, Hl = kH >> lvl;
    float val = 0.f;
#pragma unroll
    for (int k = 0; k < 3; ++k) {
      int X0 = s_ix[k*4 + lvl] + oxi;
      int Y0 = s_iy[k*4 + lvl] + oyi;
      val += s_w[k] * bil_tap(row_s, lvl_off[lvl], Wl, Hl, X0, Y0,
                              s_fx[k*4 + lvl], s_fy[k*4 + lvl]);
    }
    buf1[(size_t)(kHidden + d) * kHW + i] = val;
  }
}

// ---------------- 3x3 conv (implicit GEMM, fp32) ----------------
// in = concat(in0[C0 ch], in1[C1 ch]); out tile = 16 oc x 64 px (one row)
// mode 0: out[oc*HW + px] = acc + bias
// mode 1: atomicAdd(feat[oc], sum_px relu(acc + bias))  (no store)
__global__ __launch_bounds__(256) void conv3x3_k(const float* __restrict__ in0, int C0,
                                                 const float* __restrict__ in1, int C1,
                                                 const float* __restrict__ Wg,
                                                 const float* __restrict__ bias,
                                                 float* __restrict__ out,
                                                 float* __restrict__ feat, int mode) {
  __shared__ __align__(16) float in_s[8 * 3 * 66];   // [ci][ky][x+1]
  __shared__ __align__(16) float w_s[8 * 9 * 16];    // [(ci*9+tap)*16 + ocl]
  const int tid = threadIdx.x;
  const int w = tid & 63;
  const int ocg = tid >> 6;  // 0..3
  const int octile = blockIdx.x;
  const int row = blockIdx.y;
  const int Cin = C0 + C1;
  float acc0 = 0.f, acc1 = 0.f, acc2 = 0.f, acc3 = 0.f;

  for (int c0 = 0; c0 < Cin; c0 += 8) {
    int kc = min(8, Cin - c0);
    // stage input patch (rows row-1..row+1, cols -1..64)
    for (int idx = tid; idx < kc * 198; idx += 256) {
      int cl = idx / 198;
      int r = idx % 198;
      int ky = r / 66;
      int xx = r % 66 - 1;
      int gy = row + ky - 1;
      int c = c0 + cl;
      const float* src = (c < C0) ? (in0 + (size_t)c * kHW) : (in1 + (size_t)(c - C0) * kHW);
      float v = 0.f;
      if (gy >= 0 && gy < kH && xx >= 0 && xx < kW) v = src[gy * kW + xx];
      in_s[idx] = v;
    }
    // stage weights (transposed to [ci][tap][ocl] for float4 broadcast reads)
    for (int idx = tid; idx < kc * 144; idx += 256) {
      int ocl = idx / (kc * 9);
      int rr = idx % (kc * 9);
      int ci = rr / 9;
      int tap = rr % 9;
      w_s[(ci * 9 + tap) * 16 + ocl] =
          Wg[((size_t)(octile * 16 + ocl) * Cin + (c0 + ci)) * 9 + tap];
    }
    __syncthreads();
    if (kc == 8) {
#pragma unroll
      for (int ci = 0; ci < 8; ++ci)
#pragma unroll
        for (int ky = 0; ky < 3; ++ky)
#pragma unroll
          for (int kx = 0; kx < 3; ++kx) {
            float inv = in_s[ci * 198 + ky * 66 + w + kx];
            const float4 wv = *(const float4*)&w_s[(ci * 9 + ky * 3 + kx) * 16 + ocg * 4];
            acc0 = fmaf(inv, wv.x, acc0);
            acc1 = fmaf(inv, wv.y, acc1);
            acc2 = fmaf(inv, wv.z, acc2);
            acc3 = fmaf(inv, wv.w, acc3);
          }
    } else {
      for (int ci = 0; ci < kc; ++ci)
#pragma unroll
        for (int ky = 0; ky < 3; ++ky)
#pragma unroll
          for (int kx = 0; kx < 3; ++kx) {
            float inv = in_s[ci * 198 + ky * 66 + w + kx];
            const float4 wv = *(const float4*)&w_s[(ci * 9 + ky * 3 + kx) * 16 + ocg * 4];
            acc0 = fmaf(inv, wv.x, acc0);
            acc1 = fmaf(inv, wv.y, acc1);
            acc2 = fmaf(inv, wv.z, acc2);
            acc3 = fmaf(inv, wv.w, acc3);
          }
    }
    __syncthreads();
  }

  const int ocb = octile * 16 + ocg * 4;
  if (mode == 0) {
    out[(size_t)(ocb + 0) * kHW + row * kW + w] = acc0 + bias[ocb + 0];
    out[(size_t)(ocb + 1) * kHW + row * kW + w] = acc1 + bias[ocb + 1];
    out[(size_t)(ocb + 2) * kHW + row * kW + w] = acc2 + bias[ocb + 2];
    out[(size_t)(ocb + 3) * kHW + row * kW + w] = acc3 + bias[ocb + 3];
  } else {
    float v0 = fmaxf(acc0 + bias[ocb + 0], 0.f);
    float v1 = fmaxf(acc1 + bias[ocb + 1], 0.f);
    float v2 = fmaxf(acc2 + bias[ocb + 2], 0.f);
    float v3 = fmaxf(acc3 + bias[ocb + 3], 0.f);
#pragma unroll
    for (int off = 32; off; off >>= 1) {
      v0 += __shfl_xor(v0, off, 64);
      v1 += __shfl_xor(v1, off, 64);
      v2 += __shfl_xor(v2, off, 64);
      v3 += __shfl_xor(v3, off, 64);
    }
    if (w == 0) {
      atomicAdd(&feat[ocb + 0], v0);
      atomicAdd(&feat[ocb + 1], v1);
      atomicAdd(&feat[ocb + 2], v2);
      atomicAdd(&feat[ocb + 3], v3);
    }
  }
}

// ---------------- pointwise GRU pieces ----------------
__global__ void pw_rh_k(const float* __restrict__ rpre, const float* __restrict__ h,
                        float* __restrict__ rh) {
  int idx = blockIdx.x * blockDim.x + threadIdx.x;
  if (idx >= kHidden * kHW) return;
  float rg = 1.f / (1.f + expf(-rpre[idx]));
  rh[idx] = rg * h[idx];
}
__global__ void pw_h_k(const float* __restrict__ zpre, const float* __restrict__ qpre,
                       float* __restrict__ h) {
  int idx = blockIdx.x * blockDim.x + threadIdx.x;
  if (idx >= kHidden * kHW) return;
  float zg = 1.f / (1.f + expf(-zpre[idx]));
  float qg = tanhf(qpre[idx]);
  h[idx] = (1.f - zg) * h[idx] + zg * qg;
}

// ---------------- FC + pose update ----------------
__global__ void pose_update_k(const float* __restrict__ feat, const float* __restrict__ Wfc,
                              const float* __restrict__ bfc, float* __restrict__ pose,
                              float* __restrict__ out) {
  __shared__ float s_d[7];
  int t = threadIdx.x;
  if (t < 7) {
    float s = 0.f;
    const float inv = 1.f / (float)kHW;
    for (int k = 0; k < kHidden; ++k) s += (feat[k] * inv) * Wfc[k * 7 + t];
    s_d[t] = 0.01f * (s + bfc[t]);
  }
  __syncthreads();
  if (t != 0) return;
  float qc[4] = {pose[0], pose[1], pose[2], pose[3]};
  float tc[3] = {pose[4], pose[5], pose[6]};
  float dq[4] = {1.f + s_d[0], s_d[1], s_d[2], s_d[3]};
  float inv = 1.f / sqrtf(dq[0]*dq[0] + dq[1]*dq[1] + dq[2]*dq[2] + dq[3]*dq[3]);
  dq[0] *= inv; dq[1] *= inv; dq[2] *= inv; dq[3] *= inv;
  float dv[3] = {s_d[4], s_d[5], s_d[6]};
  float rv[3];
  d_qapply(qc, dv, rv);
  float tn[3] = {tc[0] + rv[0], tc[1] + rv[1], tc[2] + rv[2]};
  float qn[4];
  d_qmul(qc, dq, qn);
  float inv2 = 1.f / sqrtf(qn[0]*qn[0] + qn[1]*qn[1] + qn[2]*qn[2] + qn[3]*qn[3]);
  qn[0] *= inv2; qn[1] *= inv2; qn[2] *= inv2; qn[3] *= inv2;
  pose[0] = qn[0]; pose[1] = qn[1]; pose[2] = qn[2]; pose[3] = qn[3];
  pose[4] = tn[0]; pose[5] = tn[1]; pose[6] = tn[2];
  out[0] = qn[0]; out[1] = qn[1]; out[2] = qn[2]; out[3] = qn[3];
  out[4] = tn[0]; out[5] = tn[1]; out[6] = tn[2];
}

// ---------------- launch ----------------
extern "C" void kernel_launch(void* const* d_in, const int* in_sizes, int n_in,
                              void* d_out, int out_size, void* d_ws, size_t ws_size,
                              hipStream_t stream) {
  const float* frgb  = (const float*)d_in[0];
  const float* fdep  = (const float*)d_in[1];
  const float* depth = (const float*)d_in[2];
  const float* ctx   = (const float*)d_in[3];
  const float* intr  = (const float*)d_in[4];
  const float* Wz = (const float*)d_in[5];
  const float* bz = (const float*)d_in[6];
  const float* Wr = (const float*)d_in[7];
  const float* br = (const float*)d_in[8];
  const float* Wq = (const float*)d_in[9];
  const float* bq = (const float*)d_in[10];
  const float* Wh = (const float*)d_in[11];
  const float* bh = (const float*)d_in[12];
  const float* Wfc = (const float*)d_in[13];
  const float* bfc = (const float*)d_in[14];
  float* outp = (float*)d_out;

  float* ws = (float*)d_ws;
  float* corr0 = ws + OFF_CORR0;
  float* corr1 = ws + OFF_CORR1;
  float* corr2 = ws + OFF_CORR2;
  float* corr3 = ws + OFF_CORR3;
  float* X     = ws + OFF_X;
  float* buf1  = ws + OFF_BUF1;
  float* rh    = ws + OFF_RH;
  float* zpre  = ws + OFF_ZPRE;
  float* rpre  = ws + OFF_RPRE;
  float* qpre  = ws + OFF_QPRE;
  float* samp  = ws + OFF_SAMP;
  float* conf  = ws + OFF_CONF;
  float* tkw   = ws + OFF_TK;
  int*   tki   = (int*)(ws + OFF_TK + 3);
  float* pose  = ws + OFF_POSE;
  float* feat  = ws + OFF_FEAT;

  // setup
  init_k<<<1536, 256, 0, stream>>>(ctx, buf1, pose);
  corr_gemm_k<<<dim3(24, 24), 256, 0, stream>>>(fdep, frgb, corr0);
  {
    int t1 = kHW * 24 * 32, t2 = kHW * 12 * 16, t3 = kHW * 6 * 8;
    pool2_k<<<(t1 + 255) / 256, 256, 0, stream>>>(corr0, corr1, 48, 64);
    pool2_k<<<(t2 + 255) / 256, 256, 0, stream>>>(corr1, corr2, 24, 32);
    pool2_k<<<(t3 + 255) / 256, 256, 0, stream>>>(corr2, corr3, 12, 16);
  }
  xpts_k<<<12, 256, 0, stream>>>(depth, intr, X);

  for (int it = 0; it < kIters; ++it) {
    sample_poses_k<<<1, 128, 0, stream>>>(pose, samp, conf, feat);
    conf_k<<<kHW, 256, 0, stream>>>(corr0, corr1, corr2, corr3, X, samp, intr, conf);
    topk_k<<<1, 64, 0, stream>>>(conf, tkw, tki);
    fused_k<<<kHW, 256, 0, stream>>>(corr0, corr1, corr2, corr3, X, samp, intr,
                                     tkw, tki, buf1);
    conv3x3_k<<<dim3(8, 48), 256, 0, stream>>>(buf1, kGin, nullptr, 0, Wz, bz,
                                               zpre, nullptr, 0);
    conv3x3_k<<<dim3(8, 48), 256, 0, stream>>>(buf1, kGin, nullptr, 0, Wr, br,
                                               rpre, nullptr, 0);
    pw_rh_k<<<1536, 256, 0, stream>>>(rpre, buf1, rh);
    conv3x3_k<<<dim3(8, 48), 256, 0, stream>>>(rh, kHidden, buf1 + (size_t)kHidden * kHW,
                                               kCorrDim + kCtx, Wq, bq, qpre, nullptr, 0);
    pw_h_k<<<1536, 256, 0, stream>>>(zpre, qpre, buf1);
    conv3x3_k<<<dim3(8, 48), 256, 0, stream>>>(buf1, kHidden, nullptr, 0, Wh, bh,
                                               nullptr, feat, 1);
    pose_update_k<<<1, 64, 0, stream>>>(feat, Wfc, bfc, pose, outp);
  }
}

// Round 2
// 1466.965 us; speedup vs baseline: 3.1073x; 3.1073x over previous
//
#include <hip/hip_runtime.h>
#include <math.h>

// ---------------- problem constants ----------------
constexpr int kH = 48, kW = 64, kHW = 3072, kC = 256;
constexpr int kHidden = 128, kCtx = 64;
constexpr int kP = 81, kCorrDim = 324;  // 81*4
constexpr int kNS = 37, kIters = 4;
constexpr int kGin = kHidden + kCorrDim + kCtx;  // 516
constexpr int kCinPad = 544;                     // 17*32
constexpr int kStepsBig = 17 * 9;                // 153
constexpr int kStepsH = 4 * 9;                   // 36

// ---------------- workspace layout (float offsets) ----------------
constexpr size_t OFF_CORR0 = 0;                               // 3072*3072
constexpr size_t OFF_CORR1 = OFF_CORR0 + (size_t)kHW * 3072;  // 3072*768
constexpr size_t OFF_CORR2 = OFF_CORR1 + (size_t)kHW * 768;   // 3072*192
constexpr size_t OFF_CORR3 = OFF_CORR2 + (size_t)kHW * 192;   // 3072*48
constexpr size_t OFF_X     = OFF_CORR3 + (size_t)kHW * 48;    // 3072*3
constexpr size_t OFF_H     = OFF_X + (size_t)kHW * 3;         // 128*3072 planar fp32 h
constexpr size_t OFF_ZPRE  = OFF_H + (size_t)kHidden * kHW;
constexpr size_t OFF_RPRE  = OFF_ZPRE + (size_t)kHidden * kHW;  // contiguous after zpre!
constexpr size_t OFF_QPRE  = OFF_RPRE + (size_t)kHidden * kHW;
constexpr size_t OFF_BUFT  = OFF_QPRE + (size_t)kHidden * kHW;            // 3072*544 ushort
constexpr size_t OFF_PZR   = OFF_BUFT + (size_t)kHW * kCinPad / 2;        // 153*256*32 ushort
constexpr size_t OFF_PQ    = OFF_PZR + (size_t)kStepsBig * 256 * 32 / 2;  // 153*128*32 ushort
constexpr size_t OFF_PH    = OFF_PQ + (size_t)kStepsBig * 128 * 32 / 2;   // 36*128*32 ushort
constexpr size_t OFF_BZR   = OFF_PH + (size_t)kStepsH * 128 * 32 / 2;     // 256
constexpr size_t OFF_SAMP  = OFF_BZR + 256;   // 37*12
constexpr size_t OFF_CONF  = OFF_SAMP + 448;  // 37
constexpr size_t OFF_TK    = OFF_CONF + 64;   // 3 float w + 3 int idx
constexpr size_t OFF_POSE  = OFF_TK + 16;     // 7
constexpr size_t OFF_FEAT  = OFF_POSE + 16;   // 128

typedef __attribute__((ext_vector_type(8))) short short8;
typedef __attribute__((ext_vector_type(4))) float f32x4;

__device__ inline unsigned short f2b(float f) {
  unsigned int u = __float_as_uint(f);
  unsigned int r = u + 0x7FFF + ((u >> 16) & 1);
  return (unsigned short)(r >> 16);
}

// ---------------- sample templates ----------------
__constant__ float c_rot[12][3] = {
  {0,0,0},{0,0,0},{0,0,0},{0,0,0},{0,0,0},{0,0,0},
  {1,0,0},{-1,0,0},{0,1,0},{0,-1,0},{0,0,1},{0,0,-1}};
__constant__ float c_trs[12][3] = {
  {1,0,0},{-1,0,0},{0,1,0},{0,-1,0},{0,0,1},{0,0,-1},
  {0,0,0},{0,0,0},{0,0,0},{0,0,0},{0,0,0},{0,0,0}};

// ---------------- device helpers ----------------
__device__ inline void d_qmul(const float* q, const float* r, float* o) {
  o[0] = q[0]*r[0] - q[1]*r[1] - q[2]*r[2] - q[3]*r[3];
  o[1] = q[0]*r[1] + q[1]*r[0] + q[2]*r[3] - q[3]*r[2];
  o[2] = q[0]*r[2] - q[1]*r[3] + q[2]*r[0] + q[3]*r[1];
  o[3] = q[0]*r[3] + q[1]*r[2] - q[2]*r[1] + q[3]*r[0];
}
__device__ inline void d_qapply(const float* q, const float* v, float* o) {
  float a0 = -q[1]*v[0] - q[2]*v[1] - q[3]*v[2];
  float a1 =  q[0]*v[0] + q[2]*v[2] - q[3]*v[1];
  float a2 =  q[0]*v[1] - q[1]*v[2] + q[3]*v[0];
  float a3 =  q[0]*v[2] + q[1]*v[1] - q[2]*v[0];
  o[0] = -a0*q[1] + a1*q[0] - a2*q[3] + a3*q[2];
  o[1] = -a0*q[2] + a1*q[3] + a2*q[0] - a3*q[1];
  o[2] = -a0*q[3] - a1*q[2] + a2*q[1] + a3*q[0];
}
__device__ inline void d_intr(const float* intr, float& fx, float& fy, float& cx, float& cy) {
  fx = 60.f + 40.f*intr[0];
  fy = 60.f + 40.f*intr[1];
  cx = 32.f + 4.f*(intr[2] - 0.5f);
  cy = 24.f + 4.f*(intr[3] - 0.5f);
}
__device__ inline float bil_tap(const float* row_s, int base, int Wl, int Hl,
                                int X0, int Y0, float fxr, float fyr) {
  float acc = 0.f;
  float w00 = (1.f - fxr)*(1.f - fyr), w10 = fxr*(1.f - fyr);
  float w01 = (1.f - fxr)*fyr,         w11 = fxr*fyr;
  bool vx0 = (X0 >= 0) & (X0 < Wl);
  bool vx1 = (X0 + 1 >= 0) & (X0 + 1 < Wl);
  if (Y0 >= 0 && Y0 < Hl) {
    int rb = base + Y0*Wl;
    if (vx0) acc += w00 * row_s[rb + X0];
    if (vx1) acc += w10 * row_s[rb + X0 + 1];
  }
  if (Y0 + 1 >= 0 && Y0 + 1 < Hl) {
    int rb = base + (Y0 + 1)*Wl;
    if (vx0) acc += w01 * row_s[rb + X0];
    if (vx1) acc += w11 * row_s[rb + X0 + 1];
  }
  return acc;
}

// ---------------- init ----------------
__global__ void init_k(const float* __restrict__ ctx, const float* __restrict__ bz,
                       const float* __restrict__ br, float* __restrict__ h,
                       unsigned short* __restrict__ bufT, float* __restrict__ bzr,
                       float* __restrict__ pose) {
  int idx = blockIdx.x * blockDim.x + threadIdx.x;
  if (idx < kHidden * kHW) {
    h[idx] = 0.f;
    int p = idx >> 7, c = idx & 127;
    bufT[(size_t)p * kCinPad + c] = 0;
  }
  if (idx < kHW * 92) {  // ctx cols 452..515 + zero pad cols 516..543
    int p = idx / 92, c = idx % 92;
    unsigned short v = 0;
    if (c < 64) v = f2b(ctx[(size_t)c * kHW + p]);
    bufT[(size_t)p * kCinPad + 452 + c] = v;
  }
  if (idx < 256) bzr[idx] = (idx < 128) ? bz[idx] : br[idx - 128];
  if (idx == 0) {
    pose[0] = 1.f;
    for (int j = 1; j < 7; ++j) pose[j] = 0.f;
  }
}

// ---------------- weight prepack: P[s][oc][g][j], k=g*8+j, ci=cc*32+k ----------------
__global__ void pack_k(const float* __restrict__ W0, const float* __restrict__ W1,
                       int ocSplit, int OC, int nsteps, int Cin,
                       unsigned short* __restrict__ P) {
  int idx = blockIdx.x * blockDim.x + threadIdx.x;
  int total = nsteps * OC * 4;
  if (idx >= total) return;
  int g = idx & 3;
  int oc = (idx >> 2) % OC;
  int s = idx / (OC * 4);
  int cc = s / 9, tap = s % 9;
  union { unsigned short u[8]; uint4 q; } v;
#pragma unroll
  for (int j = 0; j < 8; ++j) {
    int ci = cc * 32 + g * 8 + j;
    float w = 0.f;
    if (ci < Cin)
      w = (oc < ocSplit) ? W0[((size_t)oc * Cin + ci) * 9 + tap]
                         : W1[((size_t)(oc - ocSplit) * Cin + ci) * 9 + tap];
    v.u[j] = f2b(w);
  }
  *(uint4*)&P[(size_t)idx * 8] = v.q;
}

// ---------------- corr GEMM ----------------
__global__ __launch_bounds__(256) void corr_gemm_k(const float* __restrict__ A,
                                                   const float* __restrict__ Bm,
                                                   float* __restrict__ Cg) {
  __shared__ __align__(16) float As[8 * 128];
  __shared__ __align__(16) float Bs[8 * 128];
  int tid = threadIdx.x;
  int tx = tid % 16, ty = tid / 16;
  int q0 = blockIdx.x * 128, i0 = blockIdx.y * 128;
  float acc[8][8];
#pragma unroll
  for (int r = 0; r < 8; ++r)
#pragma unroll
    for (int c = 0; c < 8; ++c) acc[r][c] = 0.f;

  int cl = tid / 32;
  int col = (tid % 32) * 4;
  for (int c0 = 0; c0 < kC; c0 += 8) {
    *(float4*)&As[cl * 128 + col] = *(const float4*)&A[(size_t)(c0 + cl) * kHW + i0 + col];
    *(float4*)&Bs[cl * 128 + col] = *(const float4*)&Bm[(size_t)(c0 + cl) * kHW + q0 + col];
    __syncthreads();
#pragma unroll
    for (int k = 0; k < 8; ++k) {
      float4 a0 = *(const float4*)&As[k * 128 + ty * 8];
      float4 a1 = *(const float4*)&As[k * 128 + ty * 8 + 4];
      float4 b0 = *(const float4*)&Bs[k * 128 + tx * 8];
      float4 b1 = *(const float4*)&Bs[k * 128 + tx * 8 + 4];
      float a[8] = {a0.x, a0.y, a0.z, a0.w, a1.x, a1.y, a1.z, a1.w};
      float b[8] = {b0.x, b0.y, b0.z, b0.w, b1.x, b1.y, b1.z, b1.w};
#pragma unroll
      for (int r = 0; r < 8; ++r)
#pragma unroll
        for (int c = 0; c < 8; ++c) acc[r][c] = fmaf(a[r], b[c], acc[r][c]);
    }
    __syncthreads();
  }
  const float S = 0.0625f;
#pragma unroll
  for (int r = 0; r < 8; ++r) {
    size_t base = (size_t)(i0 + ty * 8 + r) * kHW + q0 + tx * 8;
    float4 o0 = {acc[r][0]*S, acc[r][1]*S, acc[r][2]*S, acc[r][3]*S};
    float4 o1 = {acc[r][4]*S, acc[r][5]*S, acc[r][6]*S, acc[r][7]*S};
    *(float4*)&Cg[base] = o0;
    *(float4*)&Cg[base + 4] = o1;
  }
}

// ---------------- 2x2 avg pool ----------------
__global__ void pool2_k(const float* __restrict__ in, float* __restrict__ out,
                        int Hi, int Wi) {
  int Ho = Hi / 2, Wo = Wi / 2;
  int total = kHW * Ho * Wo;
  int idx = blockIdx.x * blockDim.x + threadIdx.x;
  if (idx >= total) return;
  int i = idx / (Ho * Wo);
  int r = idx % (Ho * Wo);
  int y = r / Wo, x = r % Wo;
  const float* p = in + (size_t)i * Hi * Wi;
  out[idx] = 0.25f * (p[(2*y)*Wi + 2*x] + p[(2*y)*Wi + 2*x + 1] +
                      p[(2*y+1)*Wi + 2*x] + p[(2*y+1)*Wi + 2*x + 1]);
}

// ---------------- back-projection ----------------
__global__ void xpts_k(const float* __restrict__ depth, const float* __restrict__ intr,
                       float* __restrict__ X) {
  int p = blockIdx.x * blockDim.x + threadIdx.x;
  if (p >= kHW) return;
  float fx, fy, cx, cy;
  d_intr(intr, fx, fy, cx, cy);
  float d = 4.f + 20.f * depth[p];
  float u = (float)(p % kW), v = (float)(p / kW);
  X[p*3+0] = (u - cx) / fx * d;
  X[p*3+1] = (v - cy) / fy * d;
  X[p*3+2] = d;
}

// ---------------- sample poses; zero conf & feat ----------------
__global__ void sample_poses_k(const float* __restrict__ pose, float* __restrict__ samp,
                               float* __restrict__ conf, float* __restrict__ feat) {
  int t = threadIdx.x;
  if (t < kNS) conf[t] = 0.f;
  if (t < kHidden) feat[t] = 0.f;
  if (t >= kNS) return;
  float qc[4] = {pose[0], pose[1], pose[2], pose[3]};
  float tc[3] = {pose[4], pose[5], pose[6]};
  float dq[4], dt[3];
  if (t == 36) {
    dq[0] = 1.f; dq[1] = dq[2] = dq[3] = 0.f;
    dt[0] = dt[1] = dt[2] = 0.f;
  } else {
    int j = t / 3, k = t % 3;
    float sc = (k == 0) ? 0.25f : ((k == 1) ? 1.f : 4.f);
    float rx = c_rot[j][0], ry = c_rot[j][1], rz = c_rot[j][2];
    float nrm = sqrtf(rx*rx + ry*ry + rz*rz);
    float axn = fmaxf(nrm, 1e-8f);
    float ax = rx / axn, ay = ry / axn, az = rz / axn;
    float ha = 0.02f * sc * 0.5f;
    float sh = sinf(ha), ch = cosf(ha);
    dq[0] = ch; dq[1] = ax * sh; dq[2] = ay * sh; dq[3] = az * sh;
    dt[0] = c_trs[j][0] * (0.02f * sc);
    dt[1] = c_trs[j][1] * (0.02f * sc);
    dt[2] = c_trs[j][2] * (0.02f * sc);
  }
  float qn[4];
  d_qmul(qc, dq, qn);
  float inv = 1.f / sqrtf(qn[0]*qn[0] + qn[1]*qn[1] + qn[2]*qn[2] + qn[3]*qn[3]);
  qn[0] *= inv; qn[1] *= inv; qn[2] *= inv; qn[3] *= inv;
  float tr[3];
  d_qapply(qc, dt, tr);
  float w = qn[0], x = qn[1], y = qn[2], z = qn[3];
  float* S = samp + t * 12;
  S[0] = 1.f - 2.f*(y*y + z*z); S[1] = 2.f*(x*y - w*z);       S[2] = 2.f*(x*z + w*y);
  S[3] = 2.f*(x*y + w*z);       S[4] = 1.f - 2.f*(x*x + z*z); S[5] = 2.f*(y*z - w*x);
  S[6] = 2.f*(x*z - w*y);       S[7] = 2.f*(y*z + w*x);       S[8] = 1.f - 2.f*(x*x + y*y);
  S[9]  = tc[0] + tr[0];
  S[10] = tc[1] + tr[1];
  S[11] = tc[2] + tr[2];
}

// ---------------- conf ----------------
__global__ __launch_bounds__(256) void conf_k(const float* __restrict__ corr0,
                                              const float* __restrict__ corr1,
                                              const float* __restrict__ corr2,
                                              const float* __restrict__ corr3,
                                              const float* __restrict__ X,
                                              const float* __restrict__ samp,
                                              const float* __restrict__ intr,
                                              float* __restrict__ conf) {
  __shared__ float row_s[4080];
  __shared__ float s_fx[kNS * 4], s_fy[kNS * 4];
  __shared__ int   s_ix[kNS * 4], s_iy[kNS * 4];
  __shared__ float s_conf[kNS];
  const int i = blockIdx.x;
  const int tid = threadIdx.x;

  for (int idx = tid; idx < 4080; idx += 256) {
    float v;
    if (idx < 3072)      v = corr0[(size_t)i * 3072 + idx];
    else if (idx < 3840) v = corr1[(size_t)i * 768 + idx - 3072];
    else if (idx < 4032) v = corr2[(size_t)i * 192 + idx - 3840];
    else                 v = corr3[(size_t)i * 48 + idx - 4032];
    row_s[idx] = v;
  }
  if (tid < kNS) {
    s_conf[tid] = 0.f;
    const float* S = samp + tid * 12;
    float X0 = X[i*3], X1 = X[i*3+1], X2 = X[i*3+2];
    float xc0 = S[0]*X0 + S[1]*X1 + S[2]*X2 + S[9];
    float xc1 = S[3]*X0 + S[4]*X1 + S[5]*X2 + S[10];
    float xc2 = S[6]*X0 + S[7]*X1 + S[8]*X2 + S[11];
    float z = fmaxf(xc2, 0.1f);
    float fx, fy, cx, cy;
    d_intr(intr, fx, fy, cx, cy);
    float u = fx * xc0 / z + cx;
    float v = fy * xc1 / z + cy;
#pragma unroll
    for (int l = 0; l < 4; ++l) {
      float s = (float)(1 << l);
      float bx = u / s, by = v / s;
      float fbx = floorf(bx), fby = floorf(by);
      s_ix[tid*4 + l] = (int)fbx;
      s_iy[tid*4 + l] = (int)fby;
      s_fx[tid*4 + l] = bx - fbx;
      s_fy[tid*4 + l] = by - fby;
    }
  }
  __syncthreads();

  const int lvl_off[4] = {0, 3072, 3840, 4032};
  for (int n = 0; n < kNS; ++n) {
    float local = 0.f;
    for (int d = tid; d < kCorrDim; d += 256) {
      int lvl = d / kP;
      int o = d % kP;
      int oyi = o / 9 - 4, oxi = o % 9 - 4;
      int Wl = kW >> lvl, Hl = kH >> lvl;
      int X0 = s_ix[n*4 + lvl] + oxi;
      int Y0 = s_iy[n*4 + lvl] + oyi;
      local += bil_tap(row_s, lvl_off[lvl], Wl, Hl, X0, Y0,
                       s_fx[n*4 + lvl], s_fy[n*4 + lvl]);
    }
#pragma unroll
    for (int off = 32; off; off >>= 1) local += __shfl_xor(local, off, 64);
    if ((tid & 63) == 0) atomicAdd(&s_conf[n], local);
  }
  __syncthreads();
  if (tid < kNS) atomicAdd(&conf[tid], s_conf[tid]);
}

// ---------------- top-k + softmax ----------------
__global__ void topk_k(const float* __restrict__ conf, float* __restrict__ tkw,
                       int* __restrict__ tki) {
  if (threadIdx.x != 0) return;
  const float scale = 1.f / ((float)kHW * (float)kCorrDim);
  float c[kNS];
  for (int n = 0; n < kNS; ++n) c[n] = conf[n] * scale;
  int id[3] = {-1, -1, -1};
  float v[3];
  for (int k = 0; k < 3; ++k) {
    float best = -1e30f;
    int bi = -1;
    for (int n = 0; n < kNS; ++n) {
      if (n == id[0] || n == id[1] || n == id[2]) continue;
      if (c[n] > best) { best = c[n]; bi = n; }
    }
    v[k] = best;
    id[k] = bi;
  }
  float m = v[0];
  float e0 = expf(v[0] - m), e1 = expf(v[1] - m), e2 = expf(v[2] - m);
  float s = e0 + e1 + e2;
  tkw[0] = e0 / s; tkw[1] = e1 / s; tkw[2] = e2 / s;
  tki[0] = id[0]; tki[1] = id[1]; tki[2] = id[2];
}

// ---------------- fused corr features -> bufT (bf16, transposed) ----------------
__global__ __launch_bounds__(256) void fused_k(const float* __restrict__ corr0,
                                               const float* __restrict__ corr1,
                                               const float* __restrict__ corr2,
                                               const float* __restrict__ corr3,
                                               const float* __restrict__ X,
                                               const float* __restrict__ samp,
                                               const float* __restrict__ intr,
                                               const float* __restrict__ tkw,
                                               const int* __restrict__ tki,
                                               unsigned short* __restrict__ bufT) {
  __shared__ float row_s[4080];
  __shared__ float s_fx[12], s_fy[12];
  __shared__ int   s_ix[12], s_iy[12];
  __shared__ float s_w[3];
  const int i = blockIdx.x;
  const int tid = threadIdx.x;

  for (int idx = tid; idx < 4080; idx += 256) {
    float v;
    if (idx < 3072)      v = corr0[(size_t)i * 3072 + idx];
    else if (idx < 3840) v = corr1[(size_t)i * 768 + idx - 3072];
    else if (idx < 4032) v = corr2[(size_t)i * 192 + idx - 3840];
    else                 v = corr3[(size_t)i * 48 + idx - 4032];
    row_s[idx] = v;
  }
  if (tid < 3) {
    int n = tki[tid];
    s_w[tid] = tkw[tid];
    const float* S = samp + n * 12;
    float X0 = X[i*3], X1 = X[i*3+1], X2 = X[i*3+2];
    float xc0 = S[0]*X0 + S[1]*X1 + S[2]*X2 + S[9];
    float xc1 = S[3]*X0 + S[4]*X1 + S[5]*X2 + S[10];
    float xc2 = S[6]*X0 + S[7]*X1 + S[8]*X2 + S[11];
    float z = fmaxf(xc2, 0.1f);
    float fx, fy, cx, cy;
    d_intr(intr, fx, fy, cx, cy);
    float u = fx * xc0 / z + cx;
    float v = fy * xc1 / z + cy;
#pragma unroll
    for (int l = 0; l < 4; ++l) {
      float s = (float)(1 << l);
      float bx = u / s, by = v / s;
      float fbx = floorf(bx), fby = floorf(by);
      s_ix[tid*4 + l] = (int)fbx;
      s_iy[tid*4 + l] = (int)fby;
      s_fx[tid*4 + l] = bx - fbx;
      s_fy[tid*4 + l] = by - fby;
    }
  }
  __syncthreads();

  const int lvl_off[4] = {0, 3072, 3840, 4032};
  for (int d = tid; d < kCorrDim; d += 256) {
    int lvl = d / kP;
    int o = d % kP;
    int oyi = o / 9 - 4, oxi = o % 9 - 4;
    int Wl = kW >> lvl, Hl = kH >> lvl;
    float val = 0.f;
#pragma unroll
    for (int k = 0; k < 3; ++k) {
      int X0 = s_ix[k*4 + lvl] + oxi;
      int Y0 = s_iy[k*4 + lvl] + oyi;
      val += s_w[k] * bil_tap(row_s, lvl_off[lvl], Wl, Hl, X0, Y0,
                              s_fx[k*4 + lvl], s_fy[k*4 + lvl]);
    }
    bufT[(size_t)i * kCinPad + kHidden + d] = f2b(val);
  }
}

// ---------------- MFMA 3x3 conv (implicit GEMM over K = taps x channels) ----------------
__global__ __launch_bounds__(256) void conv_mfma_k(const unsigned short* __restrict__ inT,
                                                   const unsigned short* __restrict__ P,
                                                   const float* __restrict__ bias,
                                                   float* __restrict__ out,
                                                   float* __restrict__ feat,
                                                   int OC, int nchunks, int mode) {
  __shared__ unsigned short tile_s[3 * 66 * 40];  // [ky][x+1][ci, pad to 40]
  const int tid = threadIdx.x;
  const int wv = tid >> 6, lane = tid & 63;
  const int y = blockIdx.y;
  const int ocBase = blockIdx.x * 64;
  const int oc0 = (wv >> 1) * 32, px0 = (wv & 1) * 32;
  const int n = lane & 15, kg = lane >> 4;

  f32x4 acc00 = {0.f, 0.f, 0.f, 0.f};
  f32x4 acc01 = {0.f, 0.f, 0.f, 0.f};
  f32x4 acc10 = {0.f, 0.f, 0.f, 0.f};
  f32x4 acc11 = {0.f, 0.f, 0.f, 0.f};

  for (int cc = 0; cc < nchunks; ++cc) {
    __syncthreads();
    for (int idx2 = tid; idx2 < 792; idx2 += 256) {  // 3*66*4 16B-chunks
      int g = idx2 & 3;
      int xx = (idx2 >> 2) % 66;
      int r = (idx2 >> 2) / 66;
      int gy = y + r - 1, gx = xx - 1;
      uint4 val = {0, 0, 0, 0};
      if (gy >= 0 && gy < kH && gx >= 0 && gx < kW)
        val = *(const uint4*)&inT[(size_t)(gy * kW + gx) * kCinPad + cc * 32 + g * 8];
      *(uint4*)&tile_s[(r * 66 + xx) * 40 + g * 8] = val;
    }
    __syncthreads();
#pragma unroll
    for (int tap = 0; tap < 9; ++tap) {
      const int ky = tap / 3, kx = tap % 3;
      const int s = cc * 9 + tap;
      short8 a0 = *(const short8*)&P[(((size_t)s * OC + ocBase + oc0 + n) * 4 + kg) * 8];
      short8 a1 = *(const short8*)&P[(((size_t)s * OC + ocBase + oc0 + 16 + n) * 4 + kg) * 8];
      short8 b0 = *(const short8*)&tile_s[(ky * 66 + px0 + n + kx) * 40 + kg * 8];
      short8 b1 = *(const short8*)&tile_s[(ky * 66 + px0 + 16 + n + kx) * 40 + kg * 8];
      acc00 = __builtin_amdgcn_mfma_f32_16x16x32_bf16(a0, b0, acc00, 0, 0, 0);
      acc01 = __builtin_amdgcn_mfma_f32_16x16x32_bf16(a0, b1, acc01, 0, 0, 0);
      acc10 = __builtin_amdgcn_mfma_f32_16x16x32_bf16(a1, b0, acc10, 0, 0, 0);
      acc11 = __builtin_amdgcn_mfma_f32_16x16x32_bf16(a1, b1, acc11, 0, 0, 0);
    }
  }

  const int colp = y * kW + px0 + n;  // C/D: col=lane&15, row=(lane>>4)*4+reg
#pragma unroll
  for (int ot = 0; ot < 2; ++ot) {
    const f32x4 aL = ot ? acc10 : acc00;
    const f32x4 aR = ot ? acc11 : acc01;
#pragma unroll
    for (int r = 0; r < 4; ++r) {
      int oc = ocBase + oc0 + ot * 16 + kg * 4 + r;
      float bv = bias[oc];
      if (mode == 0) {
        out[(size_t)oc * kHW + colp] = aL[r] + bv;
        out[(size_t)oc * kHW + colp + 16] = aR[r] + bv;
      } else {
        float v = fmaxf(aL[r] + bv, 0.f) + fmaxf(aR[r] + bv, 0.f);
        v += __shfl_xor(v, 1, 64);
        v += __shfl_xor(v, 2, 64);
        v += __shfl_xor(v, 4, 64);
        v += __shfl_xor(v, 8, 64);
        if (n == 0) atomicAdd(&feat[oc], v);
      }
    }
  }
}

// ---------------- rh = sigmoid(rpre)*h -> bufT cols 0..127 ----------------
__global__ __launch_bounds__(256) void rh_T_k(const float* __restrict__ rpre,
                                              const float* __restrict__ h,
                                              unsigned short* __restrict__ bufT) {
  __shared__ float t[64][65];
  const int tid = threadIdx.x;
  const int c0 = blockIdx.x * 64, p0 = blockIdx.y * 64;
  const int tx = tid & 63, ty = tid >> 6;
  for (int cl = ty; cl < 64; cl += 4) {
    float r = rpre[(size_t)(c0 + cl) * kHW + p0 + tx];
    float hv = h[(size_t)(c0 + cl) * kHW + p0 + tx];
    t[cl][tx] = hv / (1.f + expf(-r));
  }
  __syncthreads();
  for (int pl = ty; pl < 64; pl += 4) {
    bufT[(size_t)(p0 + pl) * kCinPad + c0 + tx] = f2b(t[tx][pl]);
  }
}

// ---------------- GRU h update: planar fp32 + bufT bf16 ----------------
__global__ __launch_bounds__(256) void h_T_k(const float* __restrict__ zpre,
                                             const float* __restrict__ qpre,
                                             float* __restrict__ h,
                                             unsigned short* __restrict__ bufT) {
  __shared__ float t[64][65];
  const int tid = threadIdx.x;
  const int c0 = blockIdx.x * 64, p0 = blockIdx.y * 64;
  const int tx = tid & 63, ty = tid >> 6;
  for (int cl = ty; cl < 64; cl += 4) {
    size_t off = (size_t)(c0 + cl) * kHW + p0 + tx;
    float zg = 1.f / (1.f + expf(-zpre[off]));
    float qg = tanhf(qpre[off]);
    float hn = (1.f - zg) * h[off] + zg * qg;
    h[off] = hn;
    t[cl][tx] = hn;
  }
  __syncthreads();
  for (int pl = ty; pl < 64; pl += 4) {
    bufT[(size_t)(p0 + pl) * kCinPad + c0 + tx] = f2b(t[tx][pl]);
  }
}

// ---------------- FC + pose update ----------------
__global__ void pose_update_k(const float* __restrict__ feat, const float* __restrict__ Wfc,
                              const float* __restrict__ bfc, float* __restrict__ pose,
                              float* __restrict__ out) {
  __shared__ float s_d[7];
  int t = threadIdx.x;
  if (t < 7) {
    float s = 0.f;
    const float inv = 1.f / (float)kHW;
    for (int k = 0; k < kHidden; ++k) s += (feat[k] * inv) * Wfc[k * 7 + t];
    s_d[t] = 0.01f * (s + bfc[t]);
  }
  __syncthreads();
  if (t != 0) return;
  float qc[4] = {pose[0], pose[1], pose[2], pose[3]};
  float tc[3] = {pose[4], pose[5], pose[6]};
  float dq[4] = {1.f + s_d[0], s_d[1], s_d[2], s_d[3]};
  float inv = 1.f / sqrtf(dq[0]*dq[0] + dq[1]*dq[1] + dq[2]*dq[2] + dq[3]*dq[3]);
  dq[0] *= inv; dq[1] *= inv; dq[2] *= inv; dq[3] *= inv;
  float dv[3] = {s_d[4], s_d[5], s_d[6]};
  float rv[3];
  d_qapply(qc, dv, rv);
  float tn[3] = {tc[0] + rv[0], tc[1] + rv[1], tc[2] + rv[2]};
  float qn[4];
  d_qmul(qc, dq, qn);
  float inv2 = 1.f / sqrtf(qn[0]*qn[0] + qn[1]*qn[1] + qn[2]*qn[2] + qn[3]*qn[3]);
  qn[0] *= inv2; qn[1] *= inv2; qn[2] *= inv2; qn[3] *= inv2;
  pose[0] = qn[0]; pose[1] = qn[1]; pose[2] = qn[2]; pose[3] = qn[3];
  pose[4] = tn[0]; pose[5] = tn[1]; pose[6] = tn[2];
  out[0] = qn[0]; out[1] = qn[1]; out[2] = qn[2]; out[3] = qn[3];
  out[4] = tn[0]; out[5] = tn[1]; out[6] = tn[2];
}

// ---------------- launch ----------------
extern "C" void kernel_launch(void* const* d_in, const int* in_sizes, int n_in,
                              void* d_out, int out_size, void* d_ws, size_t ws_size,
                              hipStream_t stream) {
  const float* frgb  = (const float*)d_in[0];
  const float* fdep  = (const float*)d_in[1];
  const float* depth = (const float*)d_in[2];
  const float* ctx   = (const float*)d_in[3];
  const float* intr  = (const float*)d_in[4];
  const float* Wz = (const float*)d_in[5];
  const float* bz = (const float*)d_in[6];
  const float* Wr = (const float*)d_in[7];
  const float* br = (const float*)d_in[8];
  const float* Wq = (const float*)d_in[9];
  const float* bq = (const float*)d_in[10];
  const float* Wh = (const float*)d_in[11];
  const float* bh = (const float*)d_in[12];
  const float* Wfc = (const float*)d_in[13];
  const float* bfc = (const float*)d_in[14];
  float* outp = (float*)d_out;

  float* ws = (float*)d_ws;
  float* corr0 = ws + OFF_CORR0;
  float* corr1 = ws + OFF_CORR1;
  float* corr2 = ws + OFF_CORR2;
  float* corr3 = ws + OFF_CORR3;
  float* X     = ws + OFF_X;
  float* hbuf  = ws + OFF_H;
  float* zpre  = ws + OFF_ZPRE;
  float* rpre  = ws + OFF_RPRE;  // contiguous after zpre
  float* qpre  = ws + OFF_QPRE;
  unsigned short* bufT = (unsigned short*)(ws + OFF_BUFT);
  unsigned short* Pzr  = (unsigned short*)(ws + OFF_PZR);
  unsigned short* Pq   = (unsigned short*)(ws + OFF_PQ);
  unsigned short* Ph   = (unsigned short*)(ws + OFF_PH);
  float* bzr   = ws + OFF_BZR;
  float* samp  = ws + OFF_SAMP;
  float* conf  = ws + OFF_CONF;
  float* tkw   = ws + OFF_TK;
  int*   tki   = (int*)(ws + OFF_TK + 3);
  float* pose  = ws + OFF_POSE;
  float* feat  = ws + OFF_FEAT;

  init_k<<<1536, 256, 0, stream>>>(ctx, bz, br, hbuf, bufT, bzr, pose);
  pack_k<<<(kStepsBig * 256 * 4 + 255) / 256, 256, 0, stream>>>(Wz, Wr, 128, 256,
                                                                kStepsBig, kGin, Pzr);
  pack_k<<<(kStepsBig * 128 * 4 + 255) / 256, 256, 0, stream>>>(Wq, Wq, 128, 128,
                                                                kStepsBig, kGin, Pq);
  pack_k<<<(kStepsH * 128 * 4 + 255) / 256, 256, 0, stream>>>(Wh, Wh, 128, 128,
                                                              kStepsH, kHidden, Ph);
  corr_gemm_k<<<dim3(24, 24), 256, 0, stream>>>(fdep, frgb, corr0);
  {
    int t1 = kHW * 24 * 32, t2 = kHW * 12 * 16, t3 = kHW * 6 * 8;
    pool2_k<<<(t1 + 255) / 256, 256, 0, stream>>>(corr0, corr1, 48, 64);
    pool2_k<<<(t2 + 255) / 256, 256, 0, stream>>>(corr1, corr2, 24, 32);
    pool2_k<<<(t3 + 255) / 256, 256, 0, stream>>>(corr2, corr3, 12, 16);
  }
  xpts_k<<<12, 256, 0, stream>>>(depth, intr, X);

  for (int it = 0; it < kIters; ++it) {
    sample_poses_k<<<1, 128, 0, stream>>>(pose, samp, conf, feat);
    conf_k<<<kHW, 256, 0, stream>>>(corr0, corr1, corr2, corr3, X, samp, intr, conf);
    topk_k<<<1, 64, 0, stream>>>(conf, tkw, tki);
    fused_k<<<kHW, 256, 0, stream>>>(corr0, corr1, corr2, corr3, X, samp, intr,
                                     tkw, tki, bufT);
    // fused z|r conv: 256 oc -> zpre | rpre (contiguous), bias table bzr = bz||br
    conv_mfma_k<<<dim3(4, 48), 256, 0, stream>>>(bufT, Pzr, bzr, zpre, nullptr, 256, 17, 0);
    rh_T_k<<<dim3(2, 48), 256, 0, stream>>>(rpre, hbuf, bufT);
    conv_mfma_k<<<dim3(2, 48), 256, 0, stream>>>(bufT, Pq, bq, qpre, nullptr, 128, 17, 0);
    h_T_k<<<dim3(2, 48), 256, 0, stream>>>(zpre, qpre, hbuf, bufT);
    conv_mfma_k<<<dim3(2, 48), 256, 0, stream>>>(bufT, Ph, bh, nullptr, feat, 128, 4, 1);
    pose_update_k<<<1, 64, 0, stream>>>(feat, Wfc, bfc, pose, outp);
  }
}

// Round 3
// 1292.618 us; speedup vs baseline: 3.5264x; 1.1349x over previous
//
#include <hip/hip_runtime.h>
#include <math.h>

// ---------------- problem constants ----------------
constexpr int kH = 48, kW = 64, kHW = 3072, kC = 256;
constexpr int kHidden = 128, kCtx = 64;
constexpr int kP = 81, kCorrDim = 324;  // 81*4
constexpr int kNS = 37, kIters = 4;
constexpr int kGin = kHidden + kCorrDim + kCtx;  // 516
constexpr int kCinPad = 544;                     // 17*32
constexpr int kStepsBig = 17 * 9;                // 153
constexpr int kStepsH = 4 * 9;                   // 36

// SAT layout (per source pixel): L0 49x65, L1 25x33, L2 13x17, L3 7x9
constexpr int kSat0 = 0, kSat1 = 3185, kSat2 = 4010, kSat3 = 4231, kSatTot = 4294;

// ---------------- workspace layout (float offsets) ----------------
constexpr size_t OFF_CORR0 = 0;                               // 3072*3072
constexpr size_t OFF_CORR1 = OFF_CORR0 + (size_t)kHW * 3072;  // 3072*768
constexpr size_t OFF_CORR2 = OFF_CORR1 + (size_t)kHW * 768;   // 3072*192
constexpr size_t OFF_CORR3 = OFF_CORR2 + (size_t)kHW * 192;   // 3072*48
constexpr size_t OFF_X     = OFF_CORR3 + (size_t)kHW * 48;    // 3072*3
constexpr size_t OFF_H     = OFF_X + (size_t)kHW * 3;         // 128*3072 planar fp32 h
constexpr size_t OFF_ZPRE  = OFF_H + (size_t)kHidden * kHW;
constexpr size_t OFF_RPRE  = OFF_ZPRE + (size_t)kHidden * kHW;  // contiguous after zpre!
constexpr size_t OFF_QPRE  = OFF_RPRE + (size_t)kHidden * kHW;
constexpr size_t OFF_BUFT  = OFF_QPRE + (size_t)kHidden * kHW;            // 3072*544 ushort
constexpr size_t OFF_PZR   = OFF_BUFT + (size_t)kHW * kCinPad / 2;        // 153*256*32 ushort
constexpr size_t OFF_PQ    = OFF_PZR + (size_t)kStepsBig * 256 * 32 / 2;  // 153*128*32 ushort
constexpr size_t OFF_PH    = OFF_PQ + (size_t)kStepsBig * 128 * 32 / 2;   // 36*128*32 ushort
constexpr size_t OFF_BZR   = OFF_PH + (size_t)kStepsH * 128 * 32 / 2;     // 256
constexpr size_t OFF_SAMP  = OFF_BZR + 256;   // 37*12
constexpr size_t OFF_CONF  = OFF_SAMP + 448;  // 37
constexpr size_t OFF_TK    = OFF_CONF + 64;   // 3 float w + 3 int idx
constexpr size_t OFF_POSE  = OFF_TK + 16;     // 7
constexpr size_t OFF_FEAT  = OFF_POSE + 16;   // 128
constexpr size_t OFF_FDT   = OFF_FEAT + 128;                  // 3072*256 ushort
constexpr size_t OFF_QT    = OFF_FDT + (size_t)kHW * kC / 2;  // 3072*256 ushort

typedef __attribute__((ext_vector_type(8))) short short8;
typedef __attribute__((ext_vector_type(4))) float f32x4;

__device__ inline unsigned short f2b(float f) {
  unsigned int u = __float_as_uint(f);
  unsigned int r = u + 0x7FFF + ((u >> 16) & 1);
  return (unsigned short)(r >> 16);
}
__device__ inline int clampi(int v, int lo, int hi) { return min(max(v, lo), hi); }

// ---------------- sample templates ----------------
__constant__ float c_rot[12][3] = {
  {0,0,0},{0,0,0},{0,0,0},{0,0,0},{0,0,0},{0,0,0},
  {1,0,0},{-1,0,0},{0,1,0},{0,-1,0},{0,0,1},{0,0,-1}};
__constant__ float c_trs[12][3] = {
  {1,0,0},{-1,0,0},{0,1,0},{0,-1,0},{0,0,1},{0,0,-1},
  {0,0,0},{0,0,0},{0,0,0},{0,0,0},{0,0,0},{0,0,0}};

// ---------------- device helpers ----------------
__device__ inline void d_qmul(const float* q, const float* r, float* o) {
  o[0] = q[0]*r[0] - q[1]*r[1] - q[2]*r[2] - q[3]*r[3];
  o[1] = q[0]*r[1] + q[1]*r[0] + q[2]*r[3] - q[3]*r[2];
  o[2] = q[0]*r[2] - q[1]*r[3] + q[2]*r[0] + q[3]*r[1];
  o[3] = q[0]*r[3] + q[1]*r[2] - q[2]*r[1] + q[3]*r[0];
}
__device__ inline void d_qapply(const float* q, const float* v, float* o) {
  float a0 = -q[1]*v[0] - q[2]*v[1] - q[3]*v[2];
  float a1 =  q[0]*v[0] + q[2]*v[2] - q[3]*v[1];
  float a2 =  q[0]*v[1] - q[1]*v[2] + q[3]*v[0];
  float a3 =  q[0]*v[2] + q[1]*v[1] - q[2]*v[0];
  o[0] = -a0*q[1] + a1*q[0] - a2*q[3] + a3*q[2];
  o[1] = -a0*q[2] + a1*q[3] + a2*q[0] - a3*q[1];
  o[2] = -a0*q[3] - a1*q[2] + a2*q[1] + a3*q[0];
}
__device__ inline void d_intr(const float* intr, float& fx, float& fy, float& cx, float& cy) {
  fx = 60.f + 40.f*intr[0];
  fy = 60.f + 40.f*intr[1];
  cx = 32.f + 4.f*(intr[2] - 0.5f);
  cy = 24.f + 4.f*(intr[3] - 0.5f);
}
__device__ inline float bil_tap(const float* row_s, int base, int Wl, int Hl,
                                int X0, int Y0, float fxr, float fyr) {
  float acc = 0.f;
  float w00 = (1.f - fxr)*(1.f - fyr), w10 = fxr*(1.f - fyr);
  float w01 = (1.f - fxr)*fyr,         w11 = fxr*fyr;
  bool vx0 = (X0 >= 0) & (X0 < Wl);
  bool vx1 = (X0 + 1 >= 0) & (X0 + 1 < Wl);
  if (Y0 >= 0 && Y0 < Hl) {
    int rb = base + Y0*Wl;
    if (vx0) acc += w00 * row_s[rb + X0];
    if (vx1) acc += w10 * row_s[rb + X0 + 1];
  }
  if (Y0 + 1 >= 0 && Y0 + 1 < Hl) {
    int rb = base + (Y0 + 1)*Wl;
    if (vx0) acc += w01 * row_s[rb + X0];
    if (vx1) acc += w11 * row_s[rb + X0 + 1];
  }
  return acc;
}

// ---------------- init ----------------
__global__ void init_k(const float* __restrict__ ctx, const float* __restrict__ bz,
                       const float* __restrict__ br, float* __restrict__ h,
                       unsigned short* __restrict__ bufT, float* __restrict__ bzr,
                       float* __restrict__ pose) {
  int idx = blockIdx.x * blockDim.x + threadIdx.x;
  if (idx < kHidden * kHW) {
    h[idx] = 0.f;
    int p = idx >> 7, c = idx & 127;
    bufT[(size_t)p * kCinPad + c] = 0;
  }
  if (idx < kHW * 92) {  // ctx cols 452..515 + zero pad cols 516..543
    int p = idx / 92, c = idx % 92;
    unsigned short v = 0;
    if (c < 64) v = f2b(ctx[(size_t)c * kHW + p]);
    bufT[(size_t)p * kCinPad + 452 + c] = v;
  }
  if (idx < 256) bzr[idx] = (idx < 128) ? bz[idx] : br[idx - 128];
  if (idx == 0) {
    pose[0] = 1.f;
    for (int j = 1; j < 7; ++j) pose[j] = 0.f;
  }
}

// ---------------- weight prepack: P[s][oc][g][j], k=g*8+j, ci=cc*32+k ----------------
__global__ void pack_k(const float* __restrict__ W0, const float* __restrict__ W1,
                       int ocSplit, int OC, int nsteps, int Cin,
                       unsigned short* __restrict__ P) {
  int idx = blockIdx.x * blockDim.x + threadIdx.x;
  int total = nsteps * OC * 4;
  if (idx >= total) return;
  int g = idx & 3;
  int oc = (idx >> 2) % OC;
  int s = idx / (OC * 4);
  int cc = s / 9, tap = s % 9;
  union { unsigned short u[8]; uint4 q; } v;
#pragma unroll
  for (int j = 0; j < 8; ++j) {
    int ci = cc * 32 + g * 8 + j;
    float w = 0.f;
    if (ci < Cin)
      w = (oc < ocSplit) ? W0[((size_t)oc * Cin + ci) * 9 + tap]
                         : W1[((size_t)(oc - ocSplit) * Cin + ci) * 9 + tap];
    v.u[j] = f2b(w);
  }
  *(uint4*)&P[(size_t)idx * 8] = v.q;
}

// ---------------- fp32 [C][HW] -> bf16 [HW][C] transpose ----------------
__global__ __launch_bounds__(256) void t_bf16_k(const float* __restrict__ src,
                                                unsigned short* __restrict__ dst) {
  __shared__ float t[64][65];
  const int tid = threadIdx.x;
  const int p0 = blockIdx.x * 64, c0 = blockIdx.y * 64;
  const int tx = tid & 63, ty = tid >> 6;
  for (int cl = ty; cl < 64; cl += 4)
    t[cl][tx] = src[(size_t)(c0 + cl) * kHW + p0 + tx];
  __syncthreads();
  for (int pl = ty; pl < 64; pl += 4)
    dst[(size_t)(p0 + pl) * kC + c0 + tx] = f2b(t[tx][pl]);
}

// ---------------- corr GEMM via MFMA: corr[i][q] = dot256(fdT[i], qT[q]) / 16 ----------------
__global__ __launch_bounds__(256) void corr_mfma_k(const unsigned short* __restrict__ fdT,
                                                   const unsigned short* __restrict__ qT,
                                                   float* __restrict__ Cg) {
  const int tid = threadIdx.x;
  const int wv = tid >> 6, lane = tid & 63;
  const int m = lane & 15, kg = lane >> 4;
  const int i0 = blockIdx.y * 128 + wv * 32;
  const int q0 = blockIdx.x * 128;

  f32x4 acc[2][8];
#pragma unroll
  for (int t = 0; t < 2; ++t)
#pragma unroll
    for (int u = 0; u < 8; ++u) acc[t][u] = (f32x4){0.f, 0.f, 0.f, 0.f};

#pragma unroll
  for (int kc = 0; kc < 8; ++kc) {
    const int kb = kc * 32 + kg * 8;
    short8 a[2], b[8];
#pragma unroll
    for (int t = 0; t < 2; ++t)
      a[t] = *(const short8*)&fdT[(size_t)(i0 + t * 16 + m) * kC + kb];
#pragma unroll
    for (int u = 0; u < 8; ++u)
      b[u] = *(const short8*)&qT[(size_t)(q0 + u * 16 + m) * kC + kb];
#pragma unroll
    for (int t = 0; t < 2; ++t)
#pragma unroll
      for (int u = 0; u < 8; ++u)
        acc[t][u] = __builtin_amdgcn_mfma_f32_16x16x32_bf16(a[t], b[u], acc[t][u], 0, 0, 0);
  }
  const float S = 0.0625f;
#pragma unroll
  for (int t = 0; t < 2; ++t)
#pragma unroll
    for (int u = 0; u < 8; ++u)
#pragma unroll
      for (int r = 0; r < 4; ++r)
        Cg[(size_t)(i0 + t * 16 + kg * 4 + r) * kHW + q0 + u * 16 + m] = acc[t][u][r] * S;
}

// ---------------- 2x2 avg pool ----------------
__global__ void pool2_k(const float* __restrict__ in, float* __restrict__ out,
                        int Hi, int Wi) {
  int Ho = Hi / 2, Wo = Wi / 2;
  int total = kHW * Ho * Wo;
  int idx = blockIdx.x * blockDim.x + threadIdx.x;
  if (idx >= total) return;
  int i = idx / (Ho * Wo);
  int r = idx % (Ho * Wo);
  int y = r / Wo, x = r % Wo;
  const float* p = in + (size_t)i * Hi * Wi;
  out[idx] = 0.25f * (p[(2*y)*Wi + 2*x] + p[(2*y)*Wi + 2*x + 1] +
                      p[(2*y+1)*Wi + 2*x] + p[(2*y+1)*Wi + 2*x + 1]);
}

// ---------------- back-projection ----------------
__global__ void xpts_k(const float* __restrict__ depth, const float* __restrict__ intr,
                       float* __restrict__ X) {
  int p = blockIdx.x * blockDim.x + threadIdx.x;
  if (p >= kHW) return;
  float fx, fy, cx, cy;
  d_intr(intr, fx, fy, cx, cy);
  float d = 4.f + 20.f * depth[p];
  float u = (float)(p % kW), v = (float)(p / kW);
  X[p*3+0] = (u - cx) / fx * d;
  X[p*3+1] = (v - cy) / fy * d;
  X[p*3+2] = d;
}

// ---------------- sample poses; zero conf & feat ----------------
__global__ void sample_poses_k(const float* __restrict__ pose, float* __restrict__ samp,
                               float* __restrict__ conf, float* __restrict__ feat) {
  int t = threadIdx.x;
  if (t < kNS) conf[t] = 0.f;
  if (t < kHidden) feat[t] = 0.f;
  if (t >= kNS) return;
  float qc[4] = {pose[0], pose[1], pose[2], pose[3]};
  float tc[3] = {pose[4], pose[5], pose[6]};
  float dq[4], dt[3];
  if (t == 36) {
    dq[0] = 1.f; dq[1] = dq[2] = dq[3] = 0.f;
    dt[0] = dt[1] = dt[2] = 0.f;
  } else {
    int j = t / 3, k = t % 3;
    float sc = (k == 0) ? 0.25f : ((k == 1) ? 1.f : 4.f);
    float rx = c_rot[j][0], ry = c_rot[j][1], rz = c_rot[j][2];
    float nrm = sqrtf(rx*rx + ry*ry + rz*rz);
    float axn = fmaxf(nrm, 1e-8f);
    float ax = rx / axn, ay = ry / axn, az = rz / axn;
    float ha = 0.02f * sc * 0.5f;
    float sh = sinf(ha), ch = cosf(ha);
    dq[0] = ch; dq[1] = ax * sh; dq[2] = ay * sh; dq[3] = az * sh;
    dt[0] = c_trs[j][0] * (0.02f * sc);
    dt[1] = c_trs[j][1] * (0.02f * sc);
    dt[2] = c_trs[j][2] * (0.02f * sc);
  }
  float qn[4];
  d_qmul(qc, dq, qn);
  float inv = 1.f / sqrtf(qn[0]*qn[0] + qn[1]*qn[1] + qn[2]*qn[2] + qn[3]*qn[3]);
  qn[0] *= inv; qn[1] *= inv; qn[2] *= inv; qn[3] *= inv;
  float tr[3];
  d_qapply(qc, dt, tr);
  float w = qn[0], x = qn[1], y = qn[2], z = qn[3];
  float* S = samp + t * 12;
  S[0] = 1.f - 2.f*(y*y + z*z); S[1] = 2.f*(x*y - w*z);       S[2] = 2.f*(x*z + w*y);
  S[3] = 2.f*(x*y + w*z);       S[4] = 1.f - 2.f*(x*x + z*z); S[5] = 2.f*(y*z - w*x);
  S[6] = 2.f*(x*z - w*y);       S[7] = 2.f*(y*z + w*x);       S[8] = 1.f - 2.f*(x*x + y*y);
  S[9]  = tc[0] + tr[0];
  S[10] = tc[1] + tr[1];
  S[11] = tc[2] + tr[2];
}

// ---------------- conf via per-pixel summed-area tables ----------------
// window-sum over 81 offsets with shared fractional part is separable:
// sum = [(1-fx)(P(xR)-P(xL)) + fx(P(xR+1)-P(xL+1))] (x) tensor (y)
__global__ __launch_bounds__(256) void conf_k(const float* __restrict__ corr0,
                                              const float* __restrict__ corr1,
                                              const float* __restrict__ corr2,
                                              const float* __restrict__ corr3,
                                              const float* __restrict__ X,
                                              const float* __restrict__ samp,
                                              const float* __restrict__ intr,
                                              float* __restrict__ conf) {
  __shared__ float sat[kSatTot];
  __shared__ float s_fx[kNS * 4], s_fy[kNS * 4];
  __shared__ int   s_ix[kNS * 4], s_iy[kNS * 4];
  __shared__ float s_conf[kNS];
  const int i = blockIdx.x;
  const int tid = threadIdx.x;
  const int wv = tid >> 6, lane = tid & 63;

  // zero top rows of each level's SAT
  if (tid < 65) sat[kSat0 + tid] = 0.f;
  else if (tid < 98) sat[kSat1 + tid - 65] = 0.f;
  else if (tid < 115) sat[kSat2 + tid - 98] = 0.f;
  else if (tid < 124) sat[kSat3 + tid - 115] = 0.f;
  if (tid < kNS) s_conf[tid] = 0.f;

  // per-sample projection
  if (tid < kNS) {
    const float* S = samp + tid * 12;
    float X0 = X[i*3], X1 = X[i*3+1], X2 = X[i*3+2];
    float xc0 = S[0]*X0 + S[1]*X1 + S[2]*X2 + S[9];
    float xc1 = S[3]*X0 + S[4]*X1 + S[5]*X2 + S[10];
    float xc2 = S[6]*X0 + S[7]*X1 + S[8]*X2 + S[11];
    float z = fmaxf(xc2, 0.1f);
    float fx, fy, cx, cy;
    d_intr(intr, fx, fy, cx, cy);
    float u = fx * xc0 / z + cx;
    float v = fy * xc1 / z + cy;
#pragma unroll
    for (int l = 0; l < 4; ++l) {
      float s = (float)(1 << l);
      float bx = u / s, by = v / s;
      float fbx = floorf(bx), fby = floorf(by);
      s_ix[tid*4 + l] = (int)fbx;
      s_iy[tid*4 + l] = (int)fby;
      s_fx[tid*4 + l] = bx - fbx;
      s_fy[tid*4 + l] = by - fby;
    }
  }

  // x-prefix scans: one wave per pyramid row, loading straight from global
  for (int r = wv; r < 90; r += 4) {
    int lvl, y;
    if (r < 48)      { lvl = 0; y = r; }
    else if (r < 72) { lvl = 1; y = r - 48; }
    else if (r < 84) { lvl = 2; y = r - 72; }
    else             { lvl = 3; y = r - 84; }
    const int Wl = kW >> lvl, Hl = kH >> lvl;
    const float* base = (lvl == 0) ? corr0 : (lvl == 1) ? corr1 : (lvl == 2) ? corr2 : corr3;
    const int so = (lvl == 0) ? kSat0 : (lvl == 1) ? kSat1 : (lvl == 2) ? kSat2 : kSat3;
    float v = (lane < Wl) ? base[(size_t)i * (Hl * Wl) + y * Wl + lane] : 0.f;
#pragma unroll
    for (int off = 1; off < 64; off <<= 1) {
      float tv = __shfl_up(v, off, 64);
      if (lane >= off) v += tv;
    }
    const int W1 = Wl + 1;
    if (lane < Wl) sat[so + (y + 1) * W1 + lane + 1] = v;
    if (lane == 0) sat[so + (y + 1) * W1] = 0.f;
  }
  __syncthreads();

  // y-prefix: one thread per column
  if (tid < 124) {
    int lvl, x;
    if (tid < 65)       { lvl = 0; x = tid; }
    else if (tid < 98)  { lvl = 1; x = tid - 65; }
    else if (tid < 115) { lvl = 2; x = tid - 98; }
    else                { lvl = 3; x = tid - 115; }
    const int Hl = kH >> lvl, W1 = (kW >> lvl) + 1;
    const int so = (lvl == 0) ? kSat0 : (lvl == 1) ? kSat1 : (lvl == 2) ? kSat2 : kSat3;
    float run = sat[so + x];
    for (int y = 1; y <= Hl; ++y) {
      run += sat[so + y * W1 + x];
      sat[so + y * W1 + x] = run;
    }
  }
  __syncthreads();

  // 16-point weighted SAT lookups per (sample, level)
  if (tid < kNS * 4) {
    const int n = tid >> 2, l = tid & 3;
    const int Wl = kW >> l, Hl = kH >> l, W1 = Wl + 1;
    const int so = (l == 0) ? kSat0 : (l == 1) ? kSat1 : (l == 2) ? kSat2 : kSat3;
    const int x0 = s_ix[tid], y0 = s_iy[tid];
    const float fx = s_fx[tid], fy = s_fy[tid];
    const int xx0 = clampi(x0 - 4, 0, Wl), xx1 = clampi(x0 - 3, 0, Wl);
    const int xx2 = clampi(x0 + 5, 0, Wl), xx3 = clampi(x0 + 6, 0, Wl);
    const int yy[4] = {clampi(y0 - 4, 0, Hl), clampi(y0 - 3, 0, Hl),
                       clampi(y0 + 5, 0, Hl), clampi(y0 + 6, 0, Hl)};
    const float cx0 = -(1.f - fx), cx1 = -fx, cx2 = 1.f - fx, cx3 = fx;
    const float cy[4] = {-(1.f - fy), -fy, 1.f - fy, fy};
    float tot = 0.f;
#pragma unroll
    for (int j = 0; j < 4; ++j) {
      const float* rowp = &sat[so + yy[j] * W1];
      float rv = cx0 * rowp[xx0] + cx1 * rowp[xx1] + cx2 * rowp[xx2] + cx3 * rowp[xx3];
      tot = fmaf(cy[j], rv, tot);
    }
    atomicAdd(&s_conf[n], tot);
  }
  __syncthreads();
  if (tid < kNS) atomicAdd(&conf[tid], s_conf[tid]);
}

// ---------------- top-k + softmax ----------------
__global__ void topk_k(const float* __restrict__ conf, float* __restrict__ tkw,
                       int* __restrict__ tki) {
  if (threadIdx.x != 0) return;
  const float scale = 1.f / ((float)kHW * (float)kCorrDim);
  float c[kNS];
  for (int n = 0; n < kNS; ++n) c[n] = conf[n] * scale;
  int id[3] = {-1, -1, -1};
  float v[3];
  for (int k = 0; k < 3; ++k) {
    float best = -1e30f;
    int bi = -1;
    for (int n = 0; n < kNS; ++n) {
      if (n == id[0] || n == id[1] || n == id[2]) continue;
      if (c[n] > best) { best = c[n]; bi = n; }
    }
    v[k] = best;
    id[k] = bi;
  }
  float m = v[0];
  float e0 = expf(v[0] - m), e1 = expf(v[1] - m), e2 = expf(v[2] - m);
  float s = e0 + e1 + e2;
  tkw[0] = e0 / s; tkw[1] = e1 / s; tkw[2] = e2 / s;
  tki[0] = id[0]; tki[1] = id[1]; tki[2] = id[2];
}

// ---------------- fused corr features -> bufT (bf16, transposed) ----------------
__global__ __launch_bounds__(256) void fused_k(const float* __restrict__ corr0,
                                               const float* __restrict__ corr1,
                                               const float* __restrict__ corr2,
                                               const float* __restrict__ corr3,
                                               const float* __restrict__ X,
                                               const float* __restrict__ samp,
                                               const float* __restrict__ intr,
                                               const float* __restrict__ tkw,
                                               const int* __restrict__ tki,
                                               unsigned short* __restrict__ bufT) {
  __shared__ float row_s[4080];
  __shared__ float s_fx[12], s_fy[12];
  __shared__ int   s_ix[12], s_iy[12];
  __shared__ float s_w[3];
  const int i = blockIdx.x;
  const int tid = threadIdx.x;

  for (int idx = tid; idx < 4080; idx += 256) {
    float v;
    if (idx < 3072)      v = corr0[(size_t)i * 3072 + idx];
    else if (idx < 3840) v = corr1[(size_t)i * 768 + idx - 3072];
    else if (idx < 4032) v = corr2[(size_t)i * 192 + idx - 3840];
    else                 v = corr3[(size_t)i * 48 + idx - 4032];
    row_s[idx] = v;
  }
  if (tid < 3) {
    int n = tki[tid];
    s_w[tid] = tkw[tid];
    const float* S = samp + n * 12;
    float X0 = X[i*3], X1 = X[i*3+1], X2 = X[i*3+2];
    float xc0 = S[0]*X0 + S[1]*X1 + S[2]*X2 + S[9];
    float xc1 = S[3]*X0 + S[4]*X1 + S[5]*X2 + S[10];
    float xc2 = S[6]*X0 + S[7]*X1 + S[8]*X2 + S[11];
    float z = fmaxf(xc2, 0.1f);
    float fx, fy, cx, cy;
    d_intr(intr, fx, fy, cx, cy);
    float u = fx * xc0 / z + cx;
    float v = fy * xc1 / z + cy;
#pragma unroll
    for (int l = 0; l < 4; ++l) {
      float s = (float)(1 << l);
      float bx = u / s, by = v / s;
      float fbx = floorf(bx), fby = floorf(by);
      s_ix[tid*4 + l] = (int)fbx;
      s_iy[tid*4 + l] = (int)fby;
      s_fx[tid*4 + l] = bx - fbx;
      s_fy[tid*4 + l] = by - fby;
    }
  }
  __syncthreads();

  const int lvl_off[4] = {0, 3072, 3840, 4032};
  for (int d = tid; d < kCorrDim; d += 256) {
    int lvl = d / kP;
    int o = d % kP;
    int oyi = o / 9 - 4, oxi = o % 9 - 4;
    int Wl = kW >> lvl, Hl = kH >> lvl;
    float val = 0.f;
#pragma unroll
    for (int k = 0; k < 3; ++k) {
      int X0 = s_ix[k*4 + lvl] + oxi;
      int Y0 = s_iy[k*4 + lvl] + oyi;
      val += s_w[k] * bil_tap(row_s, lvl_off[lvl], Wl, Hl, X0, Y0,
                              s_fx[k*4 + lvl], s_fy[k*4 + lvl]);
    }
    bufT[(size_t)i * kCinPad + kHidden + d] = f2b(val);
  }
}

// ---------------- MFMA 3x3 conv (implicit GEMM over K = taps x channels) ----------------
__global__ __launch_bounds__(256) void conv_mfma_k(const unsigned short* __restrict__ inT,
                                                   const unsigned short* __restrict__ P,
                                                   const float* __restrict__ bias,
                                                   float* __restrict__ out,
                                                   float* __restrict__ feat,
                                                   int OC, int nchunks, int mode) {
  __shared__ unsigned short tile_s[3 * 66 * 40];  // [ky][x+1][ci, pad to 40]
  const int tid = threadIdx.x;
  const int wv = tid >> 6, lane = tid & 63;
  const int y = blockIdx.y;
  const int ocBase = blockIdx.x * 64;
  const int oc0 = (wv >> 1) * 32, px0 = (wv & 1) * 32;
  const int n = lane & 15, kg = lane >> 4;

  f32x4 acc00 = {0.f, 0.f, 0.f, 0.f};
  f32x4 acc01 = {0.f, 0.f, 0.f, 0.f};
  f32x4 acc10 = {0.f, 0.f, 0.f, 0.f};
  f32x4 acc11 = {0.f, 0.f, 0.f, 0.f};

  for (int cc = 0; cc < nchunks; ++cc) {
    __syncthreads();
    for (int idx2 = tid; idx2 < 792; idx2 += 256) {  // 3*66*4 16B-chunks
      int g = idx2 & 3;
      int xx = (idx2 >> 2) % 66;
      int r = (idx2 >> 2) / 66;
      int gy = y + r - 1, gx = xx - 1;
      uint4 val = {0, 0, 0, 0};
      if (gy >= 0 && gy < kH && gx >= 0 && gx < kW)
        val = *(const uint4*)&inT[(size_t)(gy * kW + gx) * kCinPad + cc * 32 + g * 8];
      *(uint4*)&tile_s[(r * 66 + xx) * 40 + g * 8] = val;
    }
    __syncthreads();
#pragma unroll
    for (int tap = 0; tap < 9; ++tap) {
      const int ky = tap / 3, kx = tap % 3;
      const int s = cc * 9 + tap;
      short8 a0 = *(const short8*)&P[(((size_t)s * OC + ocBase + oc0 + n) * 4 + kg) * 8];
      short8 a1 = *(const short8*)&P[(((size_t)s * OC + ocBase + oc0 + 16 + n) * 4 + kg) * 8];
      short8 b0 = *(const short8*)&tile_s[(ky * 66 + px0 + n + kx) * 40 + kg * 8];
      short8 b1 = *(const short8*)&tile_s[(ky * 66 + px0 + 16 + n + kx) * 40 + kg * 8];
      acc00 = __builtin_amdgcn_mfma_f32_16x16x32_bf16(a0, b0, acc00, 0, 0, 0);
      acc01 = __builtin_amdgcn_mfma_f32_16x16x32_bf16(a0, b1, acc01, 0, 0, 0);
      acc10 = __builtin_amdgcn_mfma_f32_16x16x32_bf16(a1, b0, acc10, 0, 0, 0);
      acc11 = __builtin_amdgcn_mfma_f32_16x16x32_bf16(a1, b1, acc11, 0, 0, 0);
    }
  }

  const int colp = y * kW + px0 + n;  // C/D: col=lane&15, row=(lane>>4)*4+reg
#pragma unroll
  for (int ot = 0; ot < 2; ++ot) {
    const f32x4 aL = ot ? acc10 : acc00;
    const f32x4 aR = ot ? acc11 : acc01;
#pragma unroll
    for (int r = 0; r < 4; ++r) {
      int oc = ocBase + oc0 + ot * 16 + kg * 4 + r;
      float bv = bias[oc];
      if (mode == 0) {
        out[(size_t)oc * kHW + colp] = aL[r] + bv;
        out[(size_t)oc * kHW + colp + 16] = aR[r] + bv;
      } else {
        float v = fmaxf(aL[r] + bv, 0.f) + fmaxf(aR[r] + bv, 0.f);
        v += __shfl_xor(v, 1, 64);
        v += __shfl_xor(v, 2, 64);
        v += __shfl_xor(v, 4, 64);
        v += __shfl_xor(v, 8, 64);
        if (n == 0) atomicAdd(&feat[oc], v);
      }
    }
  }
}

// ---------------- rh = sigmoid(rpre)*h -> bufT cols 0..127 ----------------
__global__ __launch_bounds__(256) void rh_T_k(const float* __restrict__ rpre,
                                              const float* __restrict__ h,
                                              unsigned short* __restrict__ bufT) {
  __shared__ float t[64][65];
  const int tid = threadIdx.x;
  const int c0 = blockIdx.x * 64, p0 = blockIdx.y * 64;
  const int tx = tid & 63, ty = tid >> 6;
  for (int cl = ty; cl < 64; cl += 4) {
    float r = rpre[(size_t)(c0 + cl) * kHW + p0 + tx];
    float hv = h[(size_t)(c0 + cl) * kHW + p0 + tx];
    t[cl][tx] = hv / (1.f + expf(-r));
  }
  __syncthreads();
  for (int pl = ty; pl < 64; pl += 4) {
    bufT[(size_t)(p0 + pl) * kCinPad + c0 + tx] = f2b(t[tx][pl]);
  }
}

// ---------------- GRU h update: planar fp32 + bufT bf16 ----------------
__global__ __launch_bounds__(256) void h_T_k(const float* __restrict__ zpre,
                                             const float* __restrict__ qpre,
                                             float* __restrict__ h,
                                             unsigned short* __restrict__ bufT) {
  __shared__ float t[64][65];
  const int tid = threadIdx.x;
  const int c0 = blockIdx.x * 64, p0 = blockIdx.y * 64;
  const int tx = tid & 63, ty = tid >> 6;
  for (int cl = ty; cl < 64; cl += 4) {
    size_t off = (size_t)(c0 + cl) * kHW + p0 + tx;
    float zg = 1.f / (1.f + expf(-zpre[off]));
    float qg = tanhf(qpre[off]);
    float hn = (1.f - zg) * h[off] + zg * qg;
    h[off] = hn;
    t[cl][tx] = hn;
  }
  __syncthreads();
  for (int pl = ty; pl < 64; pl += 4) {
    bufT[(size_t)(p0 + pl) * kCinPad + c0 + tx] = f2b(t[tx][pl]);
  }
}

// ---------------- FC + pose update ----------------
__global__ void pose_update_k(const float* __restrict__ feat, const float* __restrict__ Wfc,
                              const float* __restrict__ bfc, float* __restrict__ pose,
                              float* __restrict__ out) {
  __shared__ float s_d[7];
  int t = threadIdx.x;
  if (t < 7) {
    float s = 0.f;
    const float inv = 1.f / (float)kHW;
    for (int k = 0; k < kHidden; ++k) s += (feat[k] * inv) * Wfc[k * 7 + t];
    s_d[t] = 0.01f * (s + bfc[t]);
  }
  __syncthreads();
  if (t != 0) return;
  float qc[4] = {pose[0], pose[1], pose[2], pose[3]};
  float tc[3] = {pose[4], pose[5], pose[6]};
  float dq[4] = {1.f + s_d[0], s_d[1], s_d[2], s_d[3]};
  float inv = 1.f / sqrtf(dq[0]*dq[0] + dq[1]*dq[1] + dq[2]*dq[2] + dq[3]*dq[3]);
  dq[0] *= inv; dq[1] *= inv; dq[2] *= inv; dq[3] *= inv;
  float dv[3] = {s_d[4], s_d[5], s_d[6]};
  float rv[3];
  d_qapply(qc, dv, rv);
  float tn[3] = {tc[0] + rv[0], tc[1] + rv[1], tc[2] + rv[2]};
  float qn[4];
  d_qmul(qc, dq, qn);
  float inv2 = 1.f / sqrtf(qn[0]*qn[0] + qn[1]*qn[1] + qn[2]*qn[2] + qn[3]*qn[3]);
  qn[0] *= inv2; qn[1] *= inv2; qn[2] *= inv2; qn[3] *= inv2;
  pose[0] = qn[0]; pose[1] = qn[1]; pose[2] = qn[2]; pose[3] = qn[3];
  pose[4] = tn[0]; pose[5] = tn[1]; pose[6] = tn[2];
  out[0] = qn[0]; out[1] = qn[1]; out[2] = qn[2]; out[3] = qn[3];
  out[4] = tn[0]; out[5] = tn[1]; out[6] = tn[2];
}

// ---------------- launch ----------------
extern "C" void kernel_launch(void* const* d_in, const int* in_sizes, int n_in,
                              void* d_out, int out_size, void* d_ws, size_t ws_size,
                              hipStream_t stream) {
  const float* frgb  = (const float*)d_in[0];
  const float* fdep  = (const float*)d_in[1];
  const float* depth = (const float*)d_in[2];
  const float* ctx   = (const float*)d_in[3];
  const float* intr  = (const float*)d_in[4];
  const float* Wz = (const float*)d_in[5];
  const float* bz = (const float*)d_in[6];
  const float* Wr = (const float*)d_in[7];
  const float* br = (const float*)d_in[8];
  const float* Wq = (const float*)d_in[9];
  const float* bq = (const float*)d_in[10];
  const float* Wh = (const float*)d_in[11];
  const float* bh = (const float*)d_in[12];
  const float* Wfc = (const float*)d_in[13];
  const float* bfc = (const float*)d_in[14];
  float* outp = (float*)d_out;

  float* ws = (float*)d_ws;
  float* corr0 = ws + OFF_CORR0;
  float* corr1 = ws + OFF_CORR1;
  float* corr2 = ws + OFF_CORR2;
  float* corr3 = ws + OFF_CORR3;
  float* X     = ws + OFF_X;
  float* hbuf  = ws + OFF_H;
  float* zpre  = ws + OFF_ZPRE;
  float* rpre  = ws + OFF_RPRE;  // contiguous after zpre
  float* qpre  = ws + OFF_QPRE;
  unsigned short* bufT = (unsigned short*)(ws + OFF_BUFT);
  unsigned short* Pzr  = (unsigned short*)(ws + OFF_PZR);
  unsigned short* Pq   = (unsigned short*)(ws + OFF_PQ);
  unsigned short* Ph   = (unsigned short*)(ws + OFF_PH);
  float* bzr   = ws + OFF_BZR;
  float* samp  = ws + OFF_SAMP;
  float* conf  = ws + OFF_CONF;
  float* tkw   = ws + OFF_TK;
  int*   tki   = (int*)(ws + OFF_TK + 3);
  float* pose  = ws + OFF_POSE;
  float* feat  = ws + OFF_FEAT;
  unsigned short* fdT = (unsigned short*)(ws + OFF_FDT);
  unsigned short* qT  = (unsigned short*)(ws + OFF_QT);

  init_k<<<1536, 256, 0, stream>>>(ctx, bz, br, hbuf, bufT, bzr, pose);
  pack_k<<<(kStepsBig * 256 * 4 + 255) / 256, 256, 0, stream>>>(Wz, Wr, 128, 256,
                                                                kStepsBig, kGin, Pzr);
  pack_k<<<(kStepsBig * 128 * 4 + 255) / 256, 256, 0, stream>>>(Wq, Wq, 128, 128,
                                                                kStepsBig, kGin, Pq);
  pack_k<<<(kStepsH * 128 * 4 + 255) / 256, 256, 0, stream>>>(Wh, Wh, 128, 128,
                                                              kStepsH, kHidden, Ph);
  t_bf16_k<<<dim3(48, 4), 256, 0, stream>>>(fdep, fdT);
  t_bf16_k<<<dim3(48, 4), 256, 0, stream>>>(frgb, qT);
  corr_mfma_k<<<dim3(24, 24), 256, 0, stream>>>(fdT, qT, corr0);
  {
    int t1 = kHW * 24 * 32, t2 = kHW * 12 * 16, t3 = kHW * 6 * 8;
    pool2_k<<<(t1 + 255) / 256, 256, 0, stream>>>(corr0, corr1, 48, 64);
    pool2_k<<<(t2 + 255) / 256, 256, 0, stream>>>(corr1, corr2, 24, 32);
    pool2_k<<<(t3 + 255) / 256, 256, 0, stream>>>(corr2, corr3, 12, 16);
  }
  xpts_k<<<12, 256, 0, stream>>>(depth, intr, X);

  for (int it = 0; it < kIters; ++it) {
    sample_poses_k<<<1, 128, 0, stream>>>(pose, samp, conf, feat);
    conf_k<<<kHW, 256, 0, stream>>>(corr0, corr1, corr2, corr3, X, samp, intr, conf);
    topk_k<<<1, 64, 0, stream>>>(conf, tkw, tki);
    fused_k<<<kHW, 256, 0, stream>>>(corr0, corr1, corr2, corr3, X, samp, intr,
                                     tkw, tki, bufT);
    conv_mfma_k<<<dim3(4, 48), 256, 0, stream>>>(bufT, Pzr, bzr, zpre, nullptr, 256, 17, 0);
    rh_T_k<<<dim3(2, 48), 256, 0, stream>>>(rpre, hbuf, bufT);
    conv_mfma_k<<<dim3(2, 48), 256, 0, stream>>>(bufT, Pq, bq, qpre, nullptr, 128, 17, 0);
    h_T_k<<<dim3(2, 48), 256, 0, stream>>>(zpre, qpre, hbuf, bufT);
    conv_mfma_k<<<dim3(2, 48), 256, 0, stream>>>(bufT, Ph, bh, nullptr, feat, 128, 4, 1);
    pose_update_k<<<1, 64, 0, stream>>>(feat, Wfc, bfc, pose, outp);
  }
}

// Round 4
// 1080.596 us; speedup vs baseline: 4.2183x; 1.1962x over previous
//
#include <hip/hip_runtime.h>
#include <math.h>

// ---------------- problem constants ----------------
constexpr int kH = 48, kW = 64, kHW = 3072, kC = 256;
constexpr int kHidden = 128, kCtx = 64;
constexpr int kP = 81, kCorrDim = 324;  // 81*4
constexpr int kNS = 37, kIters = 4;
constexpr int kGin = kHidden + kCorrDim + kCtx;  // 516
constexpr int kCinPad = 544;                     // 17*32
constexpr int kStepsBig = 17 * 9;                // 153
constexpr int kStepsH = 4 * 9;                   // 36

// SAT layout (per source pixel): L0 49x65, L1 25x33, L2 13x17, L3 7x9
constexpr int kSat0 = 0, kSat1 = 3185, kSat2 = 4010, kSat3 = 4231, kSatTot = 4294;

// ---------------- workspace layout ----------------
// ushort-unit offsets
constexpr size_t U_CORR0 = 0;                                   // 3072*3072
constexpr size_t U_CORR1 = U_CORR0 + (size_t)kHW * 3072;        // 3072*768
constexpr size_t U_CORR2 = U_CORR1 + (size_t)kHW * 768;         // 3072*192
constexpr size_t U_CORR3 = U_CORR2 + (size_t)kHW * 192;         // 3072*48
constexpr size_t U_END0  = U_CORR3 + (size_t)kHW * 48;          // 12533760
// float-unit offsets (after corr pyramid)
constexpr size_t F_X     = U_END0 / 2;                          // 3072*3
constexpr size_t F_H     = F_X + (size_t)kHW * 3;               // 128*3072
constexpr size_t F_ZPRE  = F_H + (size_t)kHidden * kHW;         // 128*3072
constexpr size_t F_END1  = F_ZPRE + (size_t)kHidden * kHW;
// ushort buffers again
constexpr size_t U_BUFT  = F_END1 * 2;                          // 3072*544
constexpr size_t U_RHT   = U_BUFT + (size_t)kHW * kCinPad;      // 3072*128
constexpr size_t U_PZR   = U_RHT + (size_t)kHW * kHidden;       // 153*256*32
constexpr size_t U_PQ    = U_PZR + (size_t)kStepsBig * 256 * 32;
constexpr size_t U_PH    = U_PQ + (size_t)kStepsBig * 128 * 32;
constexpr size_t U_END2  = U_PH + (size_t)kStepsH * 128 * 32;
// small float scalars
constexpr size_t F_BZR   = (U_END2 + 2) / 2;  // 256
constexpr size_t F_CONF  = F_BZR + 256;       // 64
constexpr size_t F_TK    = F_CONF + 64;       // 16
constexpr size_t F_POSE  = F_TK + 16;         // 16
constexpr size_t F_FEAT  = F_POSE + 16;       // 128
constexpr size_t F_END3  = F_FEAT + 128;
// transposed bf16 feature maps
constexpr size_t U_FDT   = F_END3 * 2;                   // 3072*256
constexpr size_t U_QT    = U_FDT + (size_t)kHW * kC;     // 3072*256

typedef __attribute__((ext_vector_type(8))) short short8;
typedef __attribute__((ext_vector_type(4))) float f32x4;

__device__ inline unsigned short f2b(float f) {
  unsigned int u = __float_as_uint(f);
  unsigned int r = u + 0x7FFF + ((u >> 16) & 1);
  return (unsigned short)(r >> 16);
}
__device__ inline float b2f(unsigned short u) {
  return __uint_as_float(((unsigned int)u) << 16);
}
__device__ inline int clampi(int v, int lo, int hi) { return min(max(v, lo), hi); }

// ---------------- sample templates ----------------
__constant__ float c_rot[12][3] = {
  {0,0,0},{0,0,0},{0,0,0},{0,0,0},{0,0,0},{0,0,0},
  {1,0,0},{-1,0,0},{0,1,0},{0,-1,0},{0,0,1},{0,0,-1}};
__constant__ float c_trs[12][3] = {
  {1,0,0},{-1,0,0},{0,1,0},{0,-1,0},{0,0,1},{0,0,-1},
  {0,0,0},{0,0,0},{0,0,0},{0,0,0},{0,0,0},{0,0,0}};

// ---------------- device helpers ----------------
__device__ inline void d_qmul(const float* q, const float* r, float* o) {
  o[0] = q[0]*r[0] - q[1]*r[1] - q[2]*r[2] - q[3]*r[3];
  o[1] = q[0]*r[1] + q[1]*r[0] + q[2]*r[3] - q[3]*r[2];
  o[2] = q[0]*r[2] - q[1]*r[3] + q[2]*r[0] + q[3]*r[1];
  o[3] = q[0]*r[3] + q[1]*r[2] - q[2]*r[1] + q[3]*r[0];
}
__device__ inline void d_qapply(const float* q, const float* v, float* o) {
  float a0 = -q[1]*v[0] - q[2]*v[1] - q[3]*v[2];
  float a1 =  q[0]*v[0] + q[2]*v[2] - q[3]*v[1];
  float a2 =  q[0]*v[1] - q[1]*v[2] + q[3]*v[0];
  float a3 =  q[0]*v[2] + q[1]*v[1] - q[2]*v[0];
  o[0] = -a0*q[1] + a1*q[0] - a2*q[3] + a3*q[2];
  o[1] = -a0*q[2] + a1*q[3] + a2*q[0] - a3*q[1];
  o[2] = -a0*q[3] - a1*q[2] + a2*q[1] + a3*q[0];
}
__device__ inline void d_intr(const float* intr, float& fx, float& fy, float& cx, float& cy) {
  fx = 60.f + 40.f*intr[0];
  fy = 60.f + 40.f*intr[1];
  cx = 32.f + 4.f*(intr[2] - 0.5f);
  cy = 24.f + 4.f*(intr[3] - 0.5f);
}
// pose-sample t -> S[0..8]=R, S[9..11]=t
__device__ inline void sample_Rt(int t, const float* __restrict__ pose, float* S) {
  float qc[4] = {pose[0], pose[1], pose[2], pose[3]};
  float tc[3] = {pose[4], pose[5], pose[6]};
  float dq[4], dt[3];
  if (t == 36) {
    dq[0] = 1.f; dq[1] = dq[2] = dq[3] = 0.f;
    dt[0] = dt[1] = dt[2] = 0.f;
  } else {
    int j = t / 3, k = t % 3;
    float sc = (k == 0) ? 0.25f : ((k == 1) ? 1.f : 4.f);
    float rx = c_rot[j][0], ry = c_rot[j][1], rz = c_rot[j][2];
    float nrm = sqrtf(rx*rx + ry*ry + rz*rz);
    float axn = fmaxf(nrm, 1e-8f);
    float ax = rx / axn, ay = ry / axn, az = rz / axn;
    float ha = 0.02f * sc * 0.5f;
    float sh = sinf(ha), ch = cosf(ha);
    dq[0] = ch; dq[1] = ax * sh; dq[2] = ay * sh; dq[3] = az * sh;
    dt[0] = c_trs[j][0] * (0.02f * sc);
    dt[1] = c_trs[j][1] * (0.02f * sc);
    dt[2] = c_trs[j][2] * (0.02f * sc);
  }
  float qn[4];
  d_qmul(qc, dq, qn);
  float inv = 1.f / sqrtf(qn[0]*qn[0] + qn[1]*qn[1] + qn[2]*qn[2] + qn[3]*qn[3]);
  qn[0] *= inv; qn[1] *= inv; qn[2] *= inv; qn[3] *= inv;
  float tr[3];
  d_qapply(qc, dt, tr);
  float w = qn[0], x = qn[1], y = qn[2], z = qn[3];
  S[0] = 1.f - 2.f*(y*y + z*z); S[1] = 2.f*(x*y - w*z);       S[2] = 2.f*(x*z + w*y);
  S[3] = 2.f*(x*y + w*z);       S[4] = 1.f - 2.f*(x*x + z*z); S[5] = 2.f*(y*z - w*x);
  S[6] = 2.f*(x*z - w*y);       S[7] = 2.f*(y*z + w*x);       S[8] = 1.f - 2.f*(x*x + y*y);
  S[9]  = tc[0] + tr[0];
  S[10] = tc[1] + tr[1];
  S[11] = tc[2] + tr[2];
}
__device__ inline void project_uv(const float* S, const float* Xp, const float* intr,
                                  float& u, float& v) {
  float xc0 = S[0]*Xp[0] + S[1]*Xp[1] + S[2]*Xp[2] + S[9];
  float xc1 = S[3]*Xp[0] + S[4]*Xp[1] + S[5]*Xp[2] + S[10];
  float xc2 = S[6]*Xp[0] + S[7]*Xp[1] + S[8]*Xp[2] + S[11];
  float z = fmaxf(xc2, 0.1f);
  float fx, fy, cx, cy;
  d_intr(intr, fx, fy, cx, cy);
  u = fx * xc0 / z + cx;
  v = fy * xc1 / z + cy;
}

// ---------------- init: h, bufT(h|ctx|pad), X, bzr, conf, feat, pose ----------------
__global__ void init_k(const float* __restrict__ ctx, const float* __restrict__ bz,
                       const float* __restrict__ br, const float* __restrict__ depth,
                       const float* __restrict__ intr, float* __restrict__ h,
                       unsigned short* __restrict__ bufT, float* __restrict__ bzr,
                       float* __restrict__ X, float* __restrict__ conf,
                       float* __restrict__ feat, float* __restrict__ pose) {
  int idx = blockIdx.x * blockDim.x + threadIdx.x;
  if (idx < kHidden * kHW) {
    h[idx] = 0.f;
    int p = idx >> 7, c = idx & 127;
    bufT[(size_t)p * kCinPad + c] = 0;
  }
  if (idx < kHW * 92) {  // ctx cols 452..515 + zero pad 516..543
    int p = idx / 92, c = idx % 92;
    unsigned short v = 0;
    if (c < 64) v = f2b(ctx[(size_t)c * kHW + p]);
    bufT[(size_t)p * kCinPad + 452 + c] = v;
  }
  if (idx < kHW) {
    float fx, fy, cx, cy;
    d_intr(intr, fx, fy, cx, cy);
    float d = 4.f + 20.f * depth[idx];
    float u = (float)(idx % kW), v = (float)(idx / kW);
    X[idx*3+0] = (u - cx) / fx * d;
    X[idx*3+1] = (v - cy) / fy * d;
    X[idx*3+2] = d;
  }
  if (idx < 256) bzr[idx] = (idx < 128) ? bz[idx] : br[idx - 128];
  if (idx < 64) conf[idx] = 0.f;
  if (idx < 128) feat[idx] = 0.f;
  if (idx == 0) {
    pose[0] = 1.f;
    for (int j = 1; j < 7; ++j) pose[j] = 0.f;
  }
}

// ---------------- weight prepack (tap-major): s=tap*NCH+cc, P[s][oc][g][8] ----------------
__global__ void pack_k(const float* __restrict__ W0, const float* __restrict__ W1,
                       int ocSplit, int OC, int nsteps, int nchunks, int Cin,
                       unsigned short* __restrict__ P) {
  int idx = blockIdx.x * blockDim.x + threadIdx.x;
  int total = nsteps * OC * 4;
  if (idx >= total) return;
  int g = idx & 3;
  int oc = (idx >> 2) % OC;
  int s = idx / (OC * 4);
  int tap = s / nchunks, cc = s % nchunks;
  union { unsigned short u[8]; uint4 q; } v;
#pragma unroll
  for (int j = 0; j < 8; ++j) {
    int ci = cc * 32 + g * 8 + j;
    float w = 0.f;
    if (ci < Cin)
      w = (oc < ocSplit) ? W0[((size_t)oc * Cin + ci) * 9 + tap]
                         : W1[((size_t)(oc - ocSplit) * Cin + ci) * 9 + tap];
    v.u[j] = f2b(w);
  }
  *(uint4*)&P[(size_t)idx * 8] = v.q;
}

// ---------------- fp32 [C][HW] -> bf16 [HW][C] transpose ----------------
__global__ __launch_bounds__(256) void t_bf16_k(const float* __restrict__ src,
                                                unsigned short* __restrict__ dst) {
  __shared__ float t[64][65];
  const int tid = threadIdx.x;
  const int p0 = blockIdx.x * 64, c0 = blockIdx.y * 64;
  const int tx = tid & 63, ty = tid >> 6;
  for (int cl = ty; cl < 64; cl += 4)
    t[cl][tx] = src[(size_t)(c0 + cl) * kHW + p0 + tx];
  __syncthreads();
  for (int pl = ty; pl < 64; pl += 4)
    dst[(size_t)(p0 + pl) * kC + c0 + tx] = f2b(t[tx][pl]);
}

// ---------------- corr GEMM via MFMA -> bf16 pyramid L0 ----------------
__global__ __launch_bounds__(256) void corr_mfma_k(const unsigned short* __restrict__ fdT,
                                                   const unsigned short* __restrict__ qT,
                                                   unsigned short* __restrict__ Cg) {
  const int tid = threadIdx.x;
  const int wv = tid >> 6, lane = tid & 63;
  const int m = lane & 15, kg = lane >> 4;
  const int i0 = blockIdx.y * 128 + wv * 32;
  const int q0 = blockIdx.x * 128;

  f32x4 acc[2][8];
#pragma unroll
  for (int t = 0; t < 2; ++t)
#pragma unroll
    for (int u = 0; u < 8; ++u) acc[t][u] = (f32x4){0.f, 0.f, 0.f, 0.f};

#pragma unroll
  for (int kc = 0; kc < 8; ++kc) {
    const int kb = kc * 32 + kg * 8;
    short8 a[2], b[8];
#pragma unroll
    for (int t = 0; t < 2; ++t)
      a[t] = *(const short8*)&fdT[(size_t)(i0 + t * 16 + m) * kC + kb];
#pragma unroll
    for (int u = 0; u < 8; ++u)
      b[u] = *(const short8*)&qT[(size_t)(q0 + u * 16 + m) * kC + kb];
#pragma unroll
    for (int t = 0; t < 2; ++t)
#pragma unroll
      for (int u = 0; u < 8; ++u)
        acc[t][u] = __builtin_amdgcn_mfma_f32_16x16x32_bf16(a[t], b[u], acc[t][u], 0, 0, 0);
  }
  const float S = 0.0625f;
#pragma unroll
  for (int t = 0; t < 2; ++t)
#pragma unroll
    for (int u = 0; u < 8; ++u)
#pragma unroll
      for (int r = 0; r < 4; ++r)
        Cg[(size_t)(i0 + t * 16 + kg * 4 + r) * kHW + q0 + u * 16 + m] = f2b(acc[t][u][r] * S);
}

// ---------------- 2x2 avg pool (bf16 in/out, fp32 math) ----------------
__global__ void pool2_k(const unsigned short* __restrict__ in,
                        unsigned short* __restrict__ out, int Hi, int Wi) {
  int Ho = Hi / 2, Wo = Wi / 2;
  int total = kHW * Ho * Wo;
  int idx = blockIdx.x * blockDim.x + threadIdx.x;
  if (idx >= total) return;
  int i = idx / (Ho * Wo);
  int r = idx % (Ho * Wo);
  int y = r / Wo, x = r % Wo;
  const unsigned short* p = in + (size_t)i * Hi * Wi;
  float v = 0.25f * (b2f(p[(2*y)*Wi + 2*x]) + b2f(p[(2*y)*Wi + 2*x + 1]) +
                     b2f(p[(2*y+1)*Wi + 2*x]) + b2f(p[(2*y+1)*Wi + 2*x + 1]));
  out[idx] = f2b(v);
}

// ---------------- conf via per-pixel SAT (bf16 pyramid) ----------------
template<int HL>
__device__ inline void colscan(float* sat, int so, int W1, int x) {
  float v[HL];
#pragma unroll
  for (int y = 0; y < HL; ++y) v[y] = sat[so + (y + 1) * W1 + x];
  float run = 0.f;
#pragma unroll
  for (int y = 0; y < HL; ++y) {
    run += v[y];
    sat[so + (y + 1) * W1 + x] = run;
  }
}

__global__ __launch_bounds__(256) void conf_k(const unsigned short* __restrict__ corr0,
                                              const unsigned short* __restrict__ corr1,
                                              const unsigned short* __restrict__ corr2,
                                              const unsigned short* __restrict__ corr3,
                                              const float* __restrict__ X,
                                              const float* __restrict__ pose,
                                              const float* __restrict__ intr,
                                              float* __restrict__ conf) {
  __shared__ float sat[kSatTot];
  __shared__ float s_fx[kNS * 4], s_fy[kNS * 4];
  __shared__ int   s_ix[kNS * 4], s_iy[kNS * 4];
  __shared__ float s_conf[kNS];
  const int i = blockIdx.x;
  const int tid = threadIdx.x;
  const int wv = tid >> 6, lane = tid & 63;

  // zero top rows of each level's SAT
  if (tid < 65) sat[kSat0 + tid] = 0.f;
  else if (tid < 98) sat[kSat1 + tid - 65] = 0.f;
  else if (tid < 115) sat[kSat2 + tid - 98] = 0.f;
  else if (tid < 124) sat[kSat3 + tid - 115] = 0.f;
  if (tid < kNS) s_conf[tid] = 0.f;

  // per-sample pose math + projection (redundant per block; cheap)
  if (tid < kNS) {
    float S[12];
    sample_Rt(tid, pose, S);
    float Xp[3] = {X[i*3], X[i*3+1], X[i*3+2]};
    float u, v;
    project_uv(S, Xp, intr, u, v);
#pragma unroll
    for (int l = 0; l < 4; ++l) {
      float s = (float)(1 << l);
      float bx = u / s, by = v / s;
      float fbx = floorf(bx), fby = floorf(by);
      s_ix[tid*4 + l] = (int)fbx;
      s_iy[tid*4 + l] = (int)fby;
      s_fx[tid*4 + l] = bx - fbx;
      s_fy[tid*4 + l] = by - fby;
    }
  }

  // x-prefix scans: one wave per pyramid row
  for (int r = wv; r < 90; r += 4) {
    int lvl, y;
    if (r < 48)      { lvl = 0; y = r; }
    else if (r < 72) { lvl = 1; y = r - 48; }
    else if (r < 84) { lvl = 2; y = r - 72; }
    else             { lvl = 3; y = r - 84; }
    const int Wl = kW >> lvl, Hl = kH >> lvl;
    const unsigned short* base =
        (lvl == 0) ? corr0 : (lvl == 1) ? corr1 : (lvl == 2) ? corr2 : corr3;
    const int so = (lvl == 0) ? kSat0 : (lvl == 1) ? kSat1 : (lvl == 2) ? kSat2 : kSat3;
    float v = (lane < Wl) ? b2f(base[(size_t)i * (Hl * Wl) + y * Wl + lane]) : 0.f;
#pragma unroll
    for (int off = 1; off < 64; off <<= 1) {
      float tv = __shfl_up(v, off, 64);
      if (lane >= off) v += tv;
    }
    const int W1 = Wl + 1;
    if (lane < Wl) sat[so + (y + 1) * W1 + lane + 1] = v;
    if (lane == 0) sat[so + (y + 1) * W1] = 0.f;
  }
  __syncthreads();

  // y-prefix: one thread per column, register-pipelined
  if (tid < 124) {
    if (tid < 65)       colscan<48>(sat, kSat0, 65, tid);
    else if (tid < 98)  colscan<24>(sat, kSat1, 33, tid - 65);
    else if (tid < 115) colscan<12>(sat, kSat2, 17, tid - 98);
    else                colscan<6>(sat, kSat3, 9, tid - 115);
  }
  __syncthreads();

  // 16-point weighted SAT lookups per (sample, level)
  if (tid < kNS * 4) {
    const int l = tid & 3;
    const int n = tid >> 2;
    const int Wl = kW >> l, Hl = kH >> l, W1 = Wl + 1;
    const int so = (l == 0) ? kSat0 : (l == 1) ? kSat1 : (l == 2) ? kSat2 : kSat3;
    const int x0 = s_ix[tid], y0 = s_iy[tid];
    const float fx = s_fx[tid], fy = s_fy[tid];
    const int xx0 = clampi(x0 - 4, 0, Wl), xx1 = clampi(x0 - 3, 0, Wl);
    const int xx2 = clampi(x0 + 5, 0, Wl), xx3 = clampi(x0 + 6, 0, Wl);
    const int yy[4] = {clampi(y0 - 4, 0, Hl), clampi(y0 - 3, 0, Hl),
                       clampi(y0 + 5, 0, Hl), clampi(y0 + 6, 0, Hl)};
    const float cx0 = -(1.f - fx), cx1 = -fx, cx2 = 1.f - fx, cx3 = fx;
    const float cy[4] = {-(1.f - fy), -fy, 1.f - fy, fy};
    float tot = 0.f;
#pragma unroll
    for (int j = 0; j < 4; ++j) {
      const float* rowp = &sat[so + yy[j] * W1];
      float rv = cx0 * rowp[xx0] + cx1 * rowp[xx1] + cx2 * rowp[xx2] + cx3 * rowp[xx3];
      tot = fmaf(cy[j], rv, tot);
    }
    atomicAdd(&s_conf[n], tot);
  }
  __syncthreads();
  if (tid < kNS) atomicAdd(&conf[tid], s_conf[tid]);
}

// ---------------- top-k + softmax; zeroes conf for next iter ----------------
__global__ void topk_k(float* __restrict__ conf, float* __restrict__ tkw,
                       int* __restrict__ tki) {
  if (threadIdx.x != 0) return;
  const float scale = 1.f / ((float)kHW * (float)kCorrDim);
  float c[kNS];
  for (int n = 0; n < kNS; ++n) c[n] = conf[n] * scale;
  int id[3] = {-1, -1, -1};
  float v[3];
  for (int k = 0; k < 3; ++k) {
    float best = -1e30f;
    int bi = -1;
    for (int n = 0; n < kNS; ++n) {
      if (n == id[0] || n == id[1] || n == id[2]) continue;
      if (c[n] > best) { best = c[n]; bi = n; }
    }
    v[k] = best;
    id[k] = bi;
  }
  float m = v[0];
  float e0 = expf(v[0] - m), e1 = expf(v[1] - m), e2 = expf(v[2] - m);
  float s = e0 + e1 + e2;
  tkw[0] = e0 / s; tkw[1] = e1 / s; tkw[2] = e2 / s;
  tki[0] = id[0]; tki[1] = id[1]; tki[2] = id[2];
  for (int n = 0; n < kNS; ++n) conf[n] = 0.f;
}

// ---------------- fused corr features via 10x10 windows -> bufT bf16 ----------------
__global__ __launch_bounds__(256) void fused_k(const unsigned short* __restrict__ corr0,
                                               const unsigned short* __restrict__ corr1,
                                               const unsigned short* __restrict__ corr2,
                                               const unsigned short* __restrict__ corr3,
                                               const float* __restrict__ X,
                                               const float* __restrict__ pose,
                                               const float* __restrict__ intr,
                                               const float* __restrict__ tkw,
                                               const int* __restrict__ tki,
                                               unsigned short* __restrict__ bufT) {
  __shared__ float win[12][10][12];  // [k*4+lvl][row][col(10, pad 12)]
  __shared__ float s_fx[12], s_fy[12];
  __shared__ int   s_ix[12], s_iy[12];
  __shared__ float s_w[3];
  const int i = blockIdx.x;
  const int tid = threadIdx.x;

  if (tid < 3) {
    int n = tki[tid];
    s_w[tid] = tkw[tid];
    float S[12];
    sample_Rt(n, pose, S);
    float Xp[3] = {X[i*3], X[i*3+1], X[i*3+2]};
    float u, v;
    project_uv(S, Xp, intr, u, v);
#pragma unroll
    for (int l = 0; l < 4; ++l) {
      float s = (float)(1 << l);
      float bx = u / s, by = v / s;
      float fbx = floorf(bx), fby = floorf(by);
      s_ix[tid*4 + l] = (int)fbx;
      s_iy[tid*4 + l] = (int)fby;
      s_fx[tid*4 + l] = bx - fbx;
      s_fy[tid*4 + l] = by - fby;
    }
  }
  __syncthreads();

  // stage 12 clipped 10x10 windows (zero-padded = reference validity mask)
  if (tid < 120) {
    const int w = tid / 10, rr = tid % 10;
    const int lvl = w & 3;
    const int Wl = kW >> lvl, Hl = kH >> lvl;
    const unsigned short* base =
        (lvl == 0) ? corr0 : (lvl == 1) ? corr1 : (lvl == 2) ? corr2 : corr3;
    const int y = s_iy[w] - 4 + rr;
    const bool yok = (y >= 0) && (y < Hl);
    const int xb = s_ix[w] - 4;
#pragma unroll
    for (int c = 0; c < 10; ++c) {
      const int x = xb + c;
      float v = 0.f;
      if (yok && x >= 0 && x < Wl) v = b2f(base[(size_t)i * (Hl * Wl) + y * Wl + x]);
      win[w][rr][c] = v;
    }
  }
  __syncthreads();

  for (int d = tid; d < kCorrDim; d += 256) {
    const int lvl = d / kP;
    const int o = d % kP;
    const int oyi = o / 9, oxi = o % 9;  // window-local coords (offset+4)
    float val = 0.f;
#pragma unroll
    for (int k = 0; k < 3; ++k) {
      const int w = k * 4 + lvl;
      const float fx = s_fx[w], fy = s_fy[w];
      const float w00 = (1.f - fx) * (1.f - fy), w10 = fx * (1.f - fy);
      const float w01 = (1.f - fx) * fy, w11 = fx * fy;
      val += s_w[k] * (w00 * win[w][oyi][oxi] + w10 * win[w][oyi][oxi + 1] +
                       w01 * win[w][oyi + 1][oxi] + w11 * win[w][oyi + 1][oxi + 1]);
    }
    bufT[(size_t)i * kCinPad + kHidden + d] = f2b(val);
  }
}

// ---------------- LDS-free shifted-GEMM 3x3 conv core ----------------
// block = 64 oc x 1 image row (64 px); 4 waves, each 32oc x 32px (2x2 16x16 tiles)
template<int OC, int NCH, bool QMODE>
__device__ inline void conv_kloop(const unsigned short* __restrict__ inT,
                                  const unsigned short* __restrict__ rhT,
                                  const unsigned short* __restrict__ P,
                                  int y, int wv, int lane, int ocBlock,
                                  f32x4 (&acc)[2][2]) {
  const int m = lane & 15, kg = lane >> 4;
  const int ocW = ocBlock + (wv >> 1) * 32;
  const int pxW = (wv & 1) * 32;
#pragma unroll
  for (int tap = 0; tap < 9; ++tap) {
    const int dy = tap / 3 - 1, dx = tap % 3 - 1;
    const int yy = y + dy;
    if (yy < 0 || yy >= kH) continue;
    const int xs0 = pxW + m + dx, xs1 = pxW + 16 + m + dx;
    const bool v0 = (xs0 >= 0) && (xs0 < kW);
    const bool v1 = (xs1 >= 0) && (xs1 < kW);
    const int px0 = yy * kW + xs0, px1 = yy * kW + xs1;
    const unsigned short* a_base = P + ((size_t)(tap * NCH) * OC + ocW + m) * 32 + kg * 8;
#pragma unroll
    for (int cc = 0; cc < NCH; ++cc) {
      const unsigned short* srcB;
      int stride;
      if (QMODE && cc < 4) { srcB = rhT; stride = kHidden; }
      else                 { srcB = inT; stride = kCinPad; }
      short8 a0 = *(const short8*)(a_base + (size_t)cc * OC * 32);
      short8 a1 = *(const short8*)(a_base + (size_t)cc * OC * 32 + 16 * 32);
      short8 b0 = {0, 0, 0, 0, 0, 0, 0, 0};
      short8 b1 = {0, 0, 0, 0, 0, 0, 0, 0};
      if (v0) b0 = *(const short8*)(srcB + (size_t)px0 * stride + cc * 32 + kg * 8);
      if (v1) b1 = *(const short8*)(srcB + (size_t)px1 * stride + cc * 32 + kg * 8);
      acc[0][0] = __builtin_amdgcn_mfma_f32_16x16x32_bf16(a0, b0, acc[0][0], 0, 0, 0);
      acc[0][1] = __builtin_amdgcn_mfma_f32_16x16x32_bf16(a0, b1, acc[0][1], 0, 0, 0);
      acc[1][0] = __builtin_amdgcn_mfma_f32_16x16x32_bf16(a1, b0, acc[1][0], 0, 0, 0);
      acc[1][1] = __builtin_amdgcn_mfma_f32_16x16x32_bf16(a1, b1, acc[1][1], 0, 0, 0);
    }
  }
}

// conv_zr: OC=256 -> oc<128: zpre store; oc>=128: rh = sigmoid(rpre)*h -> rhT bf16
__global__ __launch_bounds__(256) void conv_zr_k(const unsigned short* __restrict__ bufT,
                                                 const unsigned short* __restrict__ P,
                                                 const float* __restrict__ bzr,
                                                 float* __restrict__ zpre,
                                                 const float* __restrict__ hbuf,
                                                 unsigned short* __restrict__ rhT) {
  const int tid = threadIdx.x;
  const int wv = tid >> 6, lane = tid & 63;
  const int y = blockIdx.y, ocBlock = blockIdx.x * 64;
  f32x4 acc[2][2] = {{{0.f,0.f,0.f,0.f},{0.f,0.f,0.f,0.f}},
                     {{0.f,0.f,0.f,0.f},{0.f,0.f,0.f,0.f}}};
  conv_kloop<256, 17, false>(bufT, nullptr, P, y, wv, lane, ocBlock, acc);
  const int m = lane & 15, kg = lane >> 4;
  const int ocW = ocBlock + (wv >> 1) * 32, pxW = (wv & 1) * 32;
#pragma unroll
  for (int ot = 0; ot < 2; ++ot)
#pragma unroll
    for (int t = 0; t < 2; ++t)
#pragma unroll
      for (int r = 0; r < 4; ++r) {
        const int oc = ocW + ot * 16 + kg * 4 + r;
        const int px = y * kW + pxW + t * 16 + m;
        const float val = acc[ot][t][r] + bzr[oc];
        if (oc < kHidden) {
          zpre[(size_t)oc * kHW + px] = val;
        } else {
          const float rg = 1.f / (1.f + expf(-val));
          rhT[(size_t)px * kHidden + oc - kHidden] = f2b(rg * hbuf[(size_t)(oc - kHidden) * kHW + px]);
        }
      }
}

// conv_q: qpre -> GRU h update fused; writes hbuf fp32 + bufT h-cols bf16
__global__ __launch_bounds__(256) void conv_q_k(unsigned short* __restrict__ bufT,
                                                const unsigned short* __restrict__ rhT,
                                                const unsigned short* __restrict__ P,
                                                const float* __restrict__ bq,
                                                const float* __restrict__ zpre,
                                                float* __restrict__ hbuf) {
  const int tid = threadIdx.x;
  const int wv = tid >> 6, lane = tid & 63;
  const int y = blockIdx.y, ocBlock = blockIdx.x * 64;
  f32x4 acc[2][2] = {{{0.f,0.f,0.f,0.f},{0.f,0.f,0.f,0.f}},
                     {{0.f,0.f,0.f,0.f},{0.f,0.f,0.f,0.f}}};
  conv_kloop<128, 17, true>(bufT, rhT, P, y, wv, lane, ocBlock, acc);
  const int m = lane & 15, kg = lane >> 4;
  const int ocW = ocBlock + (wv >> 1) * 32, pxW = (wv & 1) * 32;
#pragma unroll
  for (int ot = 0; ot < 2; ++ot)
#pragma unroll
    for (int t = 0; t < 2; ++t)
#pragma unroll
      for (int r = 0; r < 4; ++r) {
        const int oc = ocW + ot * 16 + kg * 4 + r;
        const int px = y * kW + pxW + t * 16 + m;
        const size_t off = (size_t)oc * kHW + px;
        const float q = acc[ot][t][r] + bq[oc];
        const float zg = 1.f / (1.f + expf(-zpre[off]));
        const float hn = (1.f - zg) * hbuf[off] + zg * tanhf(q);
        hbuf[off] = hn;
        bufT[(size_t)px * kCinPad + oc] = f2b(hn);
      }
}

// conv_h: relu + spatial-mean partials -> feat atomics
__global__ __launch_bounds__(256) void conv_h_k(const unsigned short* __restrict__ bufT,
                                                const unsigned short* __restrict__ P,
                                                const float* __restrict__ bh,
                                                float* __restrict__ feat) {
  __shared__ float fb[64];
  const int tid = threadIdx.x;
  const int wv = tid >> 6, lane = tid & 63;
  const int y = blockIdx.y, ocBlock = blockIdx.x * 64;
  f32x4 acc[2][2] = {{{0.f,0.f,0.f,0.f},{0.f,0.f,0.f,0.f}},
                     {{0.f,0.f,0.f,0.f},{0.f,0.f,0.f,0.f}}};
  conv_kloop<128, 4, false>(bufT, nullptr, P, y, wv, lane, ocBlock, acc);
  if (tid < 64) fb[tid] = 0.f;
  __syncthreads();
  const int m = lane & 15, kg = lane >> 4;
  const int ocW = ocBlock + (wv >> 1) * 32;
#pragma unroll
  for (int ot = 0; ot < 2; ++ot)
#pragma unroll
    for (int r = 0; r < 4; ++r) {
      const int oc = ocW + ot * 16 + kg * 4 + r;
      const float bv = bh[oc];
      float v = fmaxf(acc[ot][0][r] + bv, 0.f) + fmaxf(acc[ot][1][r] + bv, 0.f);
      v += __shfl_xor(v, 1, 64);
      v += __shfl_xor(v, 2, 64);
      v += __shfl_xor(v, 4, 64);
      v += __shfl_xor(v, 8, 64);
      if (m == 0) atomicAdd(&fb[oc - ocBlock], v);
    }
  __syncthreads();
  if (tid < 64) atomicAdd(&feat[ocBlock + tid], fb[tid]);
}

// ---------------- FC + pose update; zeroes feat for next iter ----------------
__global__ void pose_update_k(float* __restrict__ feat, const float* __restrict__ Wfc,
                              const float* __restrict__ bfc, float* __restrict__ pose,
                              float* __restrict__ out) {
  __shared__ float s_d[7];
  int t = threadIdx.x;
  if (t < 7) {
    float s = 0.f;
    const float inv = 1.f / (float)kHW;
    for (int k = 0; k < kHidden; ++k) s += (feat[k] * inv) * Wfc[k * 7 + t];
    s_d[t] = 0.01f * (s + bfc[t]);
  }
  __syncthreads();
  if (t < kHidden) feat[t] = 0.f;
  if (t != 0) return;
  float qc[4] = {pose[0], pose[1], pose[2], pose[3]};
  float tc[3] = {pose[4], pose[5], pose[6]};
  float dq[4] = {1.f + s_d[0], s_d[1], s_d[2], s_d[3]};
  float inv = 1.f / sqrtf(dq[0]*dq[0] + dq[1]*dq[1] + dq[2]*dq[2] + dq[3]*dq[3]);
  dq[0] *= inv; dq[1] *= inv; dq[2] *= inv; dq[3] *= inv;
  float dv[3] = {s_d[4], s_d[5], s_d[6]};
  float rv[3];
  d_qapply(qc, dv, rv);
  float tn[3] = {tc[0] + rv[0], tc[1] + rv[1], tc[2] + rv[2]};
  float qn[4];
  d_qmul(qc, dq, qn);
  float inv2 = 1.f / sqrtf(qn[0]*qn[0] + qn[1]*qn[1] + qn[2]*qn[2] + qn[3]*qn[3]);
  qn[0] *= inv2; qn[1] *= inv2; qn[2] *= inv2; qn[3] *= inv2;
  pose[0] = qn[0]; pose[1] = qn[1]; pose[2] = qn[2]; pose[3] = qn[3];
  pose[4] = tn[0]; pose[5] = tn[1]; pose[6] = tn[2];
  out[0] = qn[0]; out[1] = qn[1]; out[2] = qn[2]; out[3] = qn[3];
  out[4] = tn[0]; out[5] = tn[1]; out[6] = tn[2];
}

// ---------------- launch ----------------
extern "C" void kernel_launch(void* const* d_in, const int* in_sizes, int n_in,
                              void* d_out, int out_size, void* d_ws, size_t ws_size,
                              hipStream_t stream) {
  const float* frgb  = (const float*)d_in[0];
  const float* fdep  = (const float*)d_in[1];
  const float* depth = (const float*)d_in[2];
  const float* ctx   = (const float*)d_in[3];
  const float* intr  = (const float*)d_in[4];
  const float* Wz = (const float*)d_in[5];
  const float* bz = (const float*)d_in[6];
  const float* Wr = (const float*)d_in[7];
  const float* br = (const float*)d_in[8];
  const float* Wq = (const float*)d_in[9];
  const float* bq = (const float*)d_in[10];
  const float* Wh = (const float*)d_in[11];
  const float* bh = (const float*)d_in[12];
  const float* Wfc = (const float*)d_in[13];
  const float* bfc = (const float*)d_in[14];
  float* outp = (float*)d_out;

  float* ws = (float*)d_ws;
  unsigned short* us = (unsigned short*)d_ws;
  unsigned short* corr0 = us + U_CORR0;
  unsigned short* corr1 = us + U_CORR1;
  unsigned short* corr2 = us + U_CORR2;
  unsigned short* corr3 = us + U_CORR3;
  float* X    = ws + F_X;
  float* hbuf = ws + F_H;
  float* zpre = ws + F_ZPRE;
  unsigned short* bufT = us + U_BUFT;
  unsigned short* rhT  = us + U_RHT;
  unsigned short* Pzr  = us + U_PZR;
  unsigned short* Pq   = us + U_PQ;
  unsigned short* Ph   = us + U_PH;
  float* bzr  = ws + F_BZR;
  float* conf = ws + F_CONF;
  float* tkw  = ws + F_TK;
  int*   tki  = (int*)(ws + F_TK + 3);
  float* pose = ws + F_POSE;
  float* feat = ws + F_FEAT;
  unsigned short* fdT = us + U_FDT;
  unsigned short* qT  = us + U_QT;

  init_k<<<1536, 256, 0, stream>>>(ctx, bz, br, depth, intr, hbuf, bufT, bzr, X,
                                   conf, feat, pose);
  pack_k<<<(kStepsBig * 256 * 4 + 255) / 256, 256, 0, stream>>>(Wz, Wr, 128, 256,
                                                                kStepsBig, 17, kGin, Pzr);
  pack_k<<<(kStepsBig * 128 * 4 + 255) / 256, 256, 0, stream>>>(Wq, Wq, 128, 128,
                                                                kStepsBig, 17, kGin, Pq);
  pack_k<<<(kStepsH * 128 * 4 + 255) / 256, 256, 0, stream>>>(Wh, Wh, 128, 128,
                                                              kStepsH, 4, kHidden, Ph);
  t_bf16_k<<<dim3(48, 4), 256, 0, stream>>>(fdep, fdT);
  t_bf16_k<<<dim3(48, 4), 256, 0, stream>>>(frgb, qT);
  corr_mfma_k<<<dim3(24, 24), 256, 0, stream>>>(fdT, qT, corr0);
  {
    int t1 = kHW * 24 * 32, t2 = kHW * 12 * 16, t3 = kHW * 6 * 8;
    pool2_k<<<(t1 + 255) / 256, 256, 0, stream>>>(corr0, corr1, 48, 64);
    pool2_k<<<(t2 + 255) / 256, 256, 0, stream>>>(corr1, corr2, 24, 32);
    pool2_k<<<(t3 + 255) / 256, 256, 0, stream>>>(corr2, corr3, 12, 16);
  }

  for (int it = 0; it < kIters; ++it) {
    conf_k<<<kHW, 256, 0, stream>>>(corr0, corr1, corr2, corr3, X, pose, intr, conf);
    topk_k<<<1, 64, 0, stream>>>(conf, tkw, tki);
    fused_k<<<kHW, 256, 0, stream>>>(corr0, corr1, corr2, corr3, X, pose, intr,
                                     tkw, tki, bufT);
    conv_zr_k<<<dim3(4, 48), 256, 0, stream>>>(bufT, Pzr, bzr, zpre, hbuf, rhT);
    conv_q_k<<<dim3(2, 48), 256, 0, stream>>>(bufT, rhT, Pq, bq, zpre, hbuf);
    conv_h_k<<<dim3(2, 48), 256, 0, stream>>>(bufT, Ph, bh, feat);
    pose_update_k<<<1, 128, 0, stream>>>(feat, Wfc, bfc, pose, outp);
  }
}